// Round 5
// baseline (14323.065 us; speedup 1.0000x reference)
//
#include <hip/hip_runtime.h>
#include <math.h>

#define B_ 128
#define T_ 100
#define RS 72      // padded row stride (words); data cols [4..67]; [0..3],[68..71] zero

// ---------------------------------------------------------------------------
// Fast transcendentals (~1e-6 rel err; threshold 1.27e-4)
// ---------------------------------------------------------------------------
__device__ __forceinline__ float frcp_(float x){ return __builtin_amdgcn_rcpf(x); }
__device__ __forceinline__ float fsig_(float x){ return frcp_(1.f + __expf(-x)); }
__device__ __forceinline__ float ftanh_(float x){ float e = __expf(2.f*x); return 1.f - 2.f*frcp_(e+1.f); }
__device__ __forceinline__ float gate1(float zi, float zf, float zo, float zg, float& c){
    float cc = fsig_(zf)*c + fsig_(zi)*ftanh_(zg);
    c = cc;
    return fsig_(zo)*ftanh_(cc);
}
__device__ __forceinline__ float4 ldf4(const float* p){ return *reinterpret_cast<const float4*>(p); }
__device__ __forceinline__ void stf4(float* p, float4 v){ *reinterpret_cast<float4*>(p) = v; }
__device__ __forceinline__ float4 r3(float4 o, const float* a, const float* b, const float* c){
    float4 x = ldf4(a), y = ldf4(b), z = ldf4(c);
    return make_float4(o.x+x.x+y.x+z.x, o.y+x.y+y.y+z.y,
                       o.z+x.z+y.z+z.z, o.w+x.w+y.w+z.w);
}
__device__ __forceinline__ float4 gate4(float4 zi, float4 zf, float4 zo, float4 zg,
                                        float bi, float bf, float bo, float bg, float4& c){
    float4 h;
    h.x = gate1(zi.x+bi, zf.x+bf, zo.x+bo, zg.x+bg, c.x);
    h.y = gate1(zi.y+bi, zf.y+bf, zo.y+bo, zg.y+bg, c.y);
    h.z = gate1(zi.z+bi, zf.z+bf, zo.z+bo, zg.z+bg, c.z);
    h.w = gate1(zi.w+bi, zf.w+bf, zo.w+bo, zg.w+bg, c.w);
    return h;
}

// 4 gates x 4 columns FMA: W = float4 of gate weights (i,f,o,g), u0..u3 = data
#define FMAQ(W, u0,u1,u2,u3, QI,QF,QO,QG) do{\
  QI.x=fmaf(W.x,u0,QI.x); QI.y=fmaf(W.x,u1,QI.y); QI.z=fmaf(W.x,u2,QI.z); QI.w=fmaf(W.x,u3,QI.w);\
  QF.x=fmaf(W.y,u0,QF.x); QF.y=fmaf(W.y,u1,QF.y); QF.z=fmaf(W.y,u2,QF.z); QF.w=fmaf(W.y,u3,QF.w);\
  QO.x=fmaf(W.z,u0,QO.x); QO.y=fmaf(W.z,u1,QO.y); QO.z=fmaf(W.z,u2,QO.z); QO.w=fmaf(W.z,u3,QO.w);\
  QG.x=fmaf(W.w,u0,QG.x); QG.y=fmaf(W.w,u1,QG.y); QG.z=fmaf(W.w,u2,QG.z); QG.w=fmaf(W.w,u3,QG.w);\
}while(0)

// One row, 16 output columns, all 4 gates. Acc names I0..I3,F0..F3,O0..O3,G0..G3.
#define ROW16(RP, W0, W1, W2) do{ \
  const float* rp_ = (RP); \
  float m_ = rp_[-1]; \
  float4 A_ = ldf4(rp_); float4 Bq_ = ldf4(rp_+4); \
  float4 Cq_ = ldf4(rp_+8); float4 Dq_ = ldf4(rp_+12); \
  float p_ = rp_[16]; \
  FMAQ(W1, A_.x,A_.y,A_.z,A_.w,     I0,F0,O0,G0); \
  FMAQ(W1, Bq_.x,Bq_.y,Bq_.z,Bq_.w, I1,F1,O1,G1); \
  FMAQ(W1, Cq_.x,Cq_.y,Cq_.z,Cq_.w, I2,F2,O2,G2); \
  FMAQ(W1, Dq_.x,Dq_.y,Dq_.z,Dq_.w, I3,F3,O3,G3); \
  FMAQ(W0, m_,A_.x,A_.y,A_.z,       I0,F0,O0,G0); \
  FMAQ(W0, A_.w,Bq_.x,Bq_.y,Bq_.z,  I1,F1,O1,G1); \
  FMAQ(W0, Bq_.w,Cq_.x,Cq_.y,Cq_.z, I2,F2,O2,G2); \
  FMAQ(W0, Cq_.w,Dq_.x,Dq_.y,Dq_.z, I3,F3,O3,G3); \
  FMAQ(W2, A_.y,A_.z,A_.w,Bq_.x,    I0,F0,O0,G0); \
  FMAQ(W2, Bq_.y,Bq_.z,Bq_.w,Cq_.x, I1,F1,O1,G1); \
  FMAQ(W2, Cq_.y,Cq_.z,Cq_.w,Dq_.x, I2,F2,O2,G2); \
  FMAQ(W2, Dq_.y,Dq_.z,Dq_.w,p_,    I3,F3,O3,G3); \
}while(0)

// One row, 8 output columns. Acc names I0,I1,F0,F1,O0,O1,G0,G1.
#define ROW8(RP, W0, W1, W2) do{ \
  const float* rp_ = (RP); \
  float m_ = rp_[-1]; \
  float4 A_ = ldf4(rp_); float4 Bq_ = ldf4(rp_+4); \
  float p_ = rp_[8]; \
  FMAQ(W1, A_.x,A_.y,A_.z,A_.w,     I0,F0,O0,G0); \
  FMAQ(W1, Bq_.x,Bq_.y,Bq_.z,Bq_.w, I1,F1,O1,G1); \
  FMAQ(W0, m_,A_.x,A_.y,A_.z,       I0,F0,O0,G0); \
  FMAQ(W0, A_.w,Bq_.x,Bq_.y,Bq_.z,  I1,F1,O1,G1); \
  FMAQ(W2, A_.y,A_.z,A_.w,Bq_.x,    I0,F0,O0,G0); \
  FMAQ(W2, Bq_.y,Bq_.z,Bq_.w,p_,    I1,F1,O1,G1); \
}while(0)

// ---------------------------------------------------------------------------
// Legacy helpers (xconv + fallback kernels)
// ---------------------------------------------------------------------------
__device__ __forceinline__ void fma4v(float w, float u0,float u1,float u2,float u3, float4& a){
    a.x = fmaf(w,u0,a.x); a.y = fmaf(w,u1,a.y);
    a.z = fmaf(w,u2,a.z); a.w = fmaf(w,u3,a.w);
}
__device__ __forceinline__ void fma2v(float w, float u0,float u1, float2& a){
    a.x = fmaf(w,u0,a.x); a.y = fmaf(w,u1,a.y);
}
template<int ROWS>
__device__ __forceinline__ void rowacc4(const float* __restrict__ rowp,
                                        const float* __restrict__ wk,
                                        float4& ai, float4& af, float4& ao, float4& ag)
{
    float  m = rowp[-1];
    float4 a = ldf4(rowp);
    float  p = rowp[4];
    float4 wa = ldf4(wk);
    float4 wb = ldf4(wk + ROWS);
    float4 wc = ldf4(wk + 2*ROWS);
    fma4v(wa.x, m,a.x,a.y,a.z, ai);  fma4v(wa.y, m,a.x,a.y,a.z, af);
    fma4v(wa.z, m,a.x,a.y,a.z, ao);  fma4v(wa.w, m,a.x,a.y,a.z, ag);
    fma4v(wb.x, a.x,a.y,a.z,a.w, ai); fma4v(wb.y, a.x,a.y,a.z,a.w, af);
    fma4v(wb.z, a.x,a.y,a.z,a.w, ao); fma4v(wb.w, a.x,a.y,a.z,a.w, ag);
    fma4v(wc.x, a.y,a.z,a.w,p, ai);  fma4v(wc.y, a.y,a.z,a.w,p, af);
    fma4v(wc.z, a.y,a.z,a.w,p, ao);  fma4v(wc.w, a.y,a.z,a.w,p, ag);
}
template<int ROWS>
__device__ __forceinline__ void rowacc2(const float* __restrict__ rowp,
                                        const float* __restrict__ wk,
                                        float2& ai, float2& af, float2& ao, float2& ag)
{
    float  m = rowp[-1];
    float2 a = *reinterpret_cast<const float2*>(rowp);
    float  p = rowp[2];
    float4 wa = ldf4(wk);
    float4 wb = ldf4(wk + ROWS);
    float4 wc = ldf4(wk + 2*ROWS);
    fma2v(wa.x, m,a.x, ai); fma2v(wa.y, m,a.x, af);
    fma2v(wa.z, m,a.x, ao); fma2v(wa.w, m,a.x, ag);
    fma2v(wb.x, a.x,a.y, ai); fma2v(wb.y, a.x,a.y, af);
    fma2v(wb.z, a.x,a.y, ao); fma2v(wb.w, a.x,a.y, ag);
    fma2v(wc.x, a.y,p, ai); fma2v(wc.y, a.y,p, af);
    fma2v(wc.z, a.y,p, ao); fma2v(wc.w, a.y,p, ag);
}
template<int ROWS>
__device__ __forceinline__ void rowacc8(const float* __restrict__ rowp,
                                        const float* __restrict__ wk,
                                        float4& i0, float4& i1, float4& f0v, float4& f1v,
                                        float4& o0, float4& o1, float4& g0, float4& g1)
{
    float  m = rowp[-1];
    float4 a = ldf4(rowp);
    float4 b = ldf4(rowp + 4);
    float  p = rowp[8];
    float4 wa = ldf4(wk);
    float4 wb = ldf4(wk + ROWS);
    float4 wc = ldf4(wk + 2*ROWS);
    fma4v(wa.x, m,a.x,a.y,a.z, i0);   fma4v(wa.x, a.w,b.x,b.y,b.z, i1);
    fma4v(wa.y, m,a.x,a.y,a.z, f0v);  fma4v(wa.y, a.w,b.x,b.y,b.z, f1v);
    fma4v(wa.z, m,a.x,a.y,a.z, o0);   fma4v(wa.z, a.w,b.x,b.y,b.z, o1);
    fma4v(wa.w, m,a.x,a.y,a.z, g0);   fma4v(wa.w, a.w,b.x,b.y,b.z, g1);
    fma4v(wb.x, a.x,a.y,a.z,a.w, i0); fma4v(wb.x, b.x,b.y,b.z,b.w, i1);
    fma4v(wb.y, a.x,a.y,a.z,a.w, f0v);fma4v(wb.y, b.x,b.y,b.z,b.w, f1v);
    fma4v(wb.z, a.x,a.y,a.z,a.w, o0); fma4v(wb.z, b.x,b.y,b.z,b.w, o1);
    fma4v(wb.w, a.x,a.y,a.z,a.w, g0); fma4v(wb.w, b.x,b.y,b.z,b.w, g1);
    fma4v(wc.x, a.y,a.z,a.w,b.x, i0); fma4v(wc.x, b.y,b.z,b.w,p, i1);
    fma4v(wc.y, a.y,a.z,a.w,b.x, f0v);fma4v(wc.y, b.y,b.z,b.w,p, f1v);
    fma4v(wc.z, a.y,a.z,a.w,b.x, o0); fma4v(wc.z, b.y,b.z,b.w,p, o1);
    fma4v(wc.w, a.y,a.z,a.w,b.x, g0); fma4v(wc.w, b.y,b.z,b.w,p, g1);
}

// ---------------------------------------------------------------------------
// Encoder: kg-split over K, L1 weights in VGPR, partial-z reduction via LDS.
// L0: (1+16)->16, FT=8; L1: (16+32)->32, FT=16. 512 threads, 4 barriers/step.
// hbuf rows: 0 = x, 1..16 = h0, 17..48 = h1 (contiguous for kg addressing).
// ---------------------------------------------------------------------------
__global__ __launch_bounds__(512, 2) void enc_kernel(
    const float* __restrict__ x,
    const float* __restrict__ w0, const float* __restrict__ b0,
    const float* __restrict__ w1, const float* __restrict__ b1,
    float* __restrict__ seq,
    float* __restrict__ h1f, float* __restrict__ c1f,
    float* __restrict__ h2f, float* __restrict__ c2f)
{
    __shared__ float wl0[51 * 64];
    __shared__ float bs0[64];
    __shared__ float bs1[128];
    __shared__ float hbuf[49 * RS];
    __shared__ float cb0[16 * 68];
    __shared__ float cb1[32 * 68];
    __shared__ float zs[3 * 4 * 32 * 68];

    const int tid = threadIdx.x;
    const int b = blockIdx.x;
    const int kg = tid >> 7;
    const int chA = tid & 15, f0A = ((tid >> 4) & 7) * 8;
    const int chB = tid & 31, f0B = ((tid >> 5) & 3) * 16;

    // L1 weights into registers: Wv[j][d] = gates(i,f,o,g) for row ci=kg*12+j, tap d
    float4 Wv[12][3];
#pragma unroll
    for (int j = 0; j < 12; ++j) {
        int ci = kg * 12 + j;
#pragma unroll
        for (int d = 0; d < 3; ++d) {
            Wv[j][d] = make_float4(
                w1[((0 * 32 + chB) * 48 + ci) * 9 + d * 3 + 1],
                w1[((1 * 32 + chB) * 48 + ci) * 9 + d * 3 + 1],
                w1[((2 * 32 + chB) * 48 + ci) * 9 + d * 3 + 1],
                w1[((3 * 32 + chB) * 48 + ci) * 9 + d * 3 + 1]);
        }
    }
    for (int idx = tid; idx < 51 * 64; idx += 512) {
        int k = idx >> 6, r = idx & 63;
        int ch = r >> 2, g = r & 3;
        int ci = k / 3, d = k - ci * 3;
        wl0[idx] = w0[((g * 16 + ch) * 17 + ci) * 9 + d * 3 + 1];
    }
    if (tid < 64) bs0[tid] = b0[tid];
    if (tid < 128) bs1[tid] = b1[tid];
    for (int i = tid; i < 49 * RS; i += 512) hbuf[i] = 0.f;
    for (int i = tid; i < 16 * 68; i += 512) cb0[i] = 0.f;
    for (int i = tid; i < 32 * 68; i += 512) cb1[i] = 0.f;
    __syncthreads();

    const int xl = tid - 384;       // wave 6 stages x
    float xv = 0.f;
    if (kg == 3 && xl >= 0 && xl < 64) {
        hbuf[4 + xl] = x[(b * T_ + 0) * 64 + xl];
        if (T_ > 1) xv = x[(b * T_ + 1) * 64 + xl];
    }
    __syncthreads();

    const float4 z4 = make_float4(0.f, 0.f, 0.f, 0.f);

#pragma unroll 1
    for (int t = 0; t < T_; ++t) {
        // ================= layer 0 =================
        {
            float4 I0=z4,I1=z4,F0=z4,F1=z4,O0=z4,O1=z4,G0=z4,G1=z4;
            if (kg == 0) {   // x row (ci=0), wave-uniform branch
                float4 W0 = ldf4(&wl0[0 * 64 + chA * 4]);
                float4 W1 = ldf4(&wl0[1 * 64 + chA * 4]);
                float4 W2 = ldf4(&wl0[2 * 64 + chA * 4]);
                ROW8(&hbuf[4 + f0A], W0, W1, W2);
            }
#pragma unroll
            for (int j = 0; j < 4; ++j) {
                int ci = 1 + kg * 4 + j;
                float4 W0 = ldf4(&wl0[(ci * 3 + 0) * 64 + chA * 4]);
                float4 W1 = ldf4(&wl0[(ci * 3 + 1) * 64 + chA * 4]);
                float4 W2 = ldf4(&wl0[(ci * 3 + 2) * 64 + chA * 4]);
                ROW8(&hbuf[ci * RS + 4 + f0A], W0, W1, W2);
            }
            if (kg > 0) {
                float* zp;
                zp = &zs[(((kg-1)*4 + 0)*16 + chA)*68 + f0A]; stf4(zp, I0); stf4(zp+4, I1);
                zp = &zs[(((kg-1)*4 + 1)*16 + chA)*68 + f0A]; stf4(zp, F0); stf4(zp+4, F1);
                zp = &zs[(((kg-1)*4 + 2)*16 + chA)*68 + f0A]; stf4(zp, O0); stf4(zp+4, O1);
                zp = &zs[(((kg-1)*4 + 3)*16 + chA)*68 + f0A]; stf4(zp, G0); stf4(zp+4, G1);
            }
            __syncthreads();                                   // A
            if (kg == 0) {
                const float bi = bs0[chA], bf = bs0[16+chA], bo = bs0[32+chA], bg = bs0[48+chA];
#define AZP(k,g) (&zs[(((k)*4+(g))*16 + chA)*68 + f0A])
#define AQ(q, AI,AF,AO,AG) { \
    float4 zi = r3(AI, AZP(0,0)+4*q, AZP(1,0)+4*q, AZP(2,0)+4*q); \
    float4 zf = r3(AF, AZP(0,1)+4*q, AZP(1,1)+4*q, AZP(2,1)+4*q); \
    float4 zo = r3(AO, AZP(0,2)+4*q, AZP(1,2)+4*q, AZP(2,2)+4*q); \
    float4 zg = r3(AG, AZP(0,3)+4*q, AZP(1,3)+4*q, AZP(2,3)+4*q); \
    float4 cq = ldf4(&cb0[chA*68 + f0A + 4*q]); \
    float4 hq = gate4(zi,zf,zo,zg, bi,bf,bo,bg, cq); \
    stf4(&cb0[chA*68 + f0A + 4*q], cq); \
    stf4(&hbuf[(1+chA)*RS + 4 + f0A + 4*q], hq); }
                AQ(0, I0, F0, O0, G0)
                AQ(1, I1, F1, O1, G1)
#undef AQ
#undef AZP
            }
            __syncthreads();                                   // B
        }
        // ================= layer 1 =================
        {
            float4 I0=z4,I1=z4,I2=z4,I3=z4,F0=z4,F1=z4,F2=z4,F3=z4;
            float4 O0=z4,O1=z4,O2=z4,O3=z4,G0=z4,G1=z4,G2=z4,G3=z4;
#pragma unroll
            for (int j = 0; j < 12; ++j)
                ROW16(&hbuf[(1 + kg*12 + j)*RS + 4 + f0B], Wv[j][0], Wv[j][1], Wv[j][2]);

            if (kg > 0) {
                float* zp;
                zp = &zs[(((kg-1)*4 + 0)*32 + chB)*68 + f0B];
                stf4(zp, I0); stf4(zp+4, I1); stf4(zp+8, I2); stf4(zp+12, I3);
                zp = &zs[(((kg-1)*4 + 1)*32 + chB)*68 + f0B];
                stf4(zp, F0); stf4(zp+4, F1); stf4(zp+8, F2); stf4(zp+12, F3);
                zp = &zs[(((kg-1)*4 + 2)*32 + chB)*68 + f0B];
                stf4(zp, O0); stf4(zp+4, O1); stf4(zp+8, O2); stf4(zp+12, O3);
                zp = &zs[(((kg-1)*4 + 3)*32 + chB)*68 + f0B];
                stf4(zp, G0); stf4(zp+4, G1); stf4(zp+8, G2); stf4(zp+12, G3);
            }
            if (kg == 3 && xl >= 0 && xl < 64) {   // stage x(t+1) into row 0
                hbuf[4 + xl] = xv;
                if (t + 2 < T_) xv = x[(b * T_ + t + 2) * 64 + xl];
            }
            __syncthreads();                                   // C
            if (kg == 0) {
                const float bi = bs1[chB], bf = bs1[32+chB], bo = bs1[64+chB], bg = bs1[96+chB];
                float* seqp = &seq[((size_t)t * B_ + b) * 2048 + chB * 64 + f0B];
#define EZP(k,g) (&zs[(((k)*4+(g))*32 + chB)*68 + f0B])
#define EQ(q, AI,AF,AO,AG) { \
    float4 zi = r3(AI, EZP(0,0)+4*q, EZP(1,0)+4*q, EZP(2,0)+4*q); \
    float4 zf = r3(AF, EZP(0,1)+4*q, EZP(1,1)+4*q, EZP(2,1)+4*q); \
    float4 zo = r3(AO, EZP(0,2)+4*q, EZP(1,2)+4*q, EZP(2,2)+4*q); \
    float4 zg = r3(AG, EZP(0,3)+4*q, EZP(1,3)+4*q, EZP(2,3)+4*q); \
    float4 cq = ldf4(&cb1[chB*68 + f0B + 4*q]); \
    float4 hq = gate4(zi,zf,zo,zg, bi,bf,bo,bg, cq); \
    stf4(&cb1[chB*68 + f0B + 4*q], cq); \
    stf4(&hbuf[(17+chB)*RS + 4 + f0B + 4*q], hq); \
    stf4(seqp + 4*q, hq); }
                EQ(0, I0, F0, O0, G0)
                EQ(1, I1, F1, O1, G1)
                EQ(2, I2, F2, O2, G2)
                EQ(3, I3, F3, O3, G3)
#undef EQ
#undef EZP
            }
            __syncthreads();                                   // D
        }
    }

    // final states
    for (int i = tid; i < 1024; i += 512) {
        int ch = i >> 6, f = i & 63;
        h1f[b * 1024 + i] = hbuf[(1 + ch) * RS + 4 + f];
        c1f[b * 1024 + i] = cb0[ch * 68 + f];
    }
    for (int i = tid; i < 2048; i += 512) {
        int ch = i >> 6, f = i & 63;
        h2f[b * 2048 + i] = hbuf[(17 + ch) * RS + 4 + f];
        c2f[b * 2048 + i] = cb1[ch * 68 + f];
    }
}

// ---------------------------------------------------------------------------
// xconv0: parallel x-part pre-activations for dec0. One block per (t,b).
// ---------------------------------------------------------------------------
__global__ __launch_bounds__(256, 2) void xconv0_kernel(
    const float* __restrict__ seqIn, const float* __restrict__ w,
    float* __restrict__ zx, int t0)
{
    __shared__ float wl[96 * 128];
    __shared__ float xt[32 * RS];

    const int tid = threadIdx.x;
    const int tl = blockIdx.x / B_;
    const int b  = blockIdx.x - tl * B_;
    const int t  = t0 + tl;

    for (int idx = tid; idx < 96 * 128; idx += 256) {
        int k = idx >> 7, r = idx & 127;
        int ch = r >> 2, g = r & 3;
        int ci = k / 3, d = k - ci * 3;
        wl[idx] = w[((g * 32 + ch) * 64 + ci) * 9 + d * 3 + 1];
    }
    {
        int r = tid >> 3, j = tid & 7;
        xt[r * RS + (j < 4 ? j : 64 + j)] = 0.f;
    }
    {
        const float* s = &seqIn[((size_t)t * B_ + b) * 2048 + tid * 8];
        float4 v0 = ldf4(s);
        float4 v1 = ldf4(s + 4);
        int ci = tid >> 3, col = (tid & 7) * 8;
        stf4(&xt[ci * RS + 4 + col], v0);
        stf4(&xt[ci * RS + 4 + col + 4], v1);
    }
    __syncthreads();

    const int ch = tid >> 3, f0 = (tid & 7) * 8;
    const float4 z4 = make_float4(0.f,0.f,0.f,0.f);
    float4 i0=z4,i1=z4,f0v=z4,f1v=z4,o0=z4,o1=z4,g0=z4,g1=z4;
#pragma unroll 1
    for (int r = 0; r < 32; ++r)
        rowacc8<128>(&xt[r * RS + 4 + f0], wl + (r * 3) * 128 + ch * 4,
                     i0, i1, f0v, f1v, o0, o1, g0, g1);

    float* zp = &zx[(((size_t)tl * B_ + b) * 4) * 2048 + ch * 64 + f0];
    stf4(zp, i0);            stf4(zp + 4, i1);
    stf4(zp + 2048, f0v);    stf4(zp + 2048 + 4, f1v);
    stf4(zp + 4096, o0);     stf4(zp + 4096 + 4, o1);
    stf4(zp + 6144, g0);     stf4(zp + 6144 + 4, g1);
}

// ---------------------------------------------------------------------------
// xconv1: parallel x-part for dec1 (32 -> 16ch). One block per (t,b).
// ---------------------------------------------------------------------------
__global__ __launch_bounds__(256, 2) void xconv1_kernel(
    const float* __restrict__ seqIn, const float* __restrict__ w,
    float* __restrict__ zx, int t0)
{
    __shared__ float wl[96 * 64];
    __shared__ float xt[32 * RS];

    const int tid = threadIdx.x;
    const int tl = blockIdx.x / B_;
    const int b  = blockIdx.x - tl * B_;
    const int t  = t0 + tl;

    for (int idx = tid; idx < 96 * 64; idx += 256) {
        int k = idx >> 6, r = idx & 63;
        int ch = r >> 2, g = r & 3;
        int ci = k / 3, d = k - ci * 3;
        wl[idx] = w[((g * 16 + ch) * 48 + ci) * 9 + d * 3 + 1];
    }
    {
        int r = tid >> 3, j = tid & 7;
        xt[r * RS + (j < 4 ? j : 64 + j)] = 0.f;
    }
    {
        const float* s = &seqIn[((size_t)t * B_ + b) * 2048 + tid * 8];
        float4 v0 = ldf4(s);
        float4 v1 = ldf4(s + 4);
        int ci = tid >> 3, col = (tid & 7) * 8;
        stf4(&xt[ci * RS + 4 + col], v0);
        stf4(&xt[ci * RS + 4 + col + 4], v1);
    }
    __syncthreads();

    const int ch = tid >> 4, f0 = (tid & 15) * 4;
    const float4 z4 = make_float4(0.f,0.f,0.f,0.f);
    float4 ai=z4, af=z4, ao=z4, ag=z4;
#pragma unroll 1
    for (int r = 0; r < 32; ++r)
        rowacc4<64>(&xt[r * RS + 4 + f0], wl + (r * 3) * 64 + ch * 4, ai, af, ao, ag);

    float* zp = &zx[(((size_t)tl * B_ + b) * 4) * 1024 + ch * 64 + f0];
    stf4(zp, ai);
    stf4(zp + 1024, af);
    stf4(zp + 2048, ao);
    stf4(zp + 3072, ag);
}

// ---------------------------------------------------------------------------
// dec0k: decoder L0 recurrence (h-part only), kg-split, weights in VGPR.
// (32h)->32, FT=16. seq updated in place. 2 barriers/step.
// ---------------------------------------------------------------------------
__global__ __launch_bounds__(512, 2) void dec0k(
    const float* __restrict__ w, const float* __restrict__ bias,
    float* __restrict__ seq, const float* __restrict__ zx,
    const float* __restrict__ hin, const float* __restrict__ cin,
    float* __restrict__ hout, float* __restrict__ cout,
    int t0, int tn)
{
    __shared__ float hp[32 * RS];
    __shared__ float cb[32 * 68];
    __shared__ float zs[3 * 4 * 32 * 68];
    __shared__ float bs[128];

    const int tid = threadIdx.x, b = blockIdx.x;
    const int kg = tid >> 7, ch = tid & 31, f0 = ((tid >> 5) & 3) * 16;

    float4 Wv[8][3];
#pragma unroll
    for (int j = 0; j < 8; ++j) {
        int ci = 32 + kg * 8 + j;
#pragma unroll
        for (int d = 0; d < 3; ++d)
            Wv[j][d] = make_float4(
                w[((0 * 32 + ch) * 64 + ci) * 9 + d * 3 + 1],
                w[((1 * 32 + ch) * 64 + ci) * 9 + d * 3 + 1],
                w[((2 * 32 + ch) * 64 + ci) * 9 + d * 3 + 1],
                w[((3 * 32 + ch) * 64 + ci) * 9 + d * 3 + 1]);
    }
    if (tid < 128) bs[tid] = bias[tid];
    for (int i = tid; i < 32 * RS; i += 512) hp[i] = 0.f;
    __syncthreads();
    for (int i = tid; i < 2048; i += 512) {
        int c8 = i >> 6, f = i & 63;
        hp[c8 * RS + 4 + f] = hin[b * 2048 + i];
        cb[c8 * 68 + f] = cin[b * 2048 + i];
    }
    __syncthreads();

    const float4 z4 = make_float4(0.f, 0.f, 0.f, 0.f);

#pragma unroll 1
    for (int tl = 0; tl < tn; ++tl) {
        const int t = t0 + tl;
        float4 I0=z4,I1=z4,I2=z4,I3=z4,F0=z4,F1=z4,F2=z4,F3=z4;
        float4 O0=z4,O1=z4,O2=z4,O3=z4,G0=z4,G1=z4,G2=z4,G3=z4;
        // x-part pre-activations seed kg1 (i,f) / kg2 (o,g) accumulators
        const float* zp0 = &zx[((size_t)tl * B_ + b) * 8192 + ch * 64 + f0];
        if (kg == 1) {
            I0 = ldf4(zp0);        I1 = ldf4(zp0+4);      I2 = ldf4(zp0+8);      I3 = ldf4(zp0+12);
            F0 = ldf4(zp0+2048);   F1 = ldf4(zp0+2052);   F2 = ldf4(zp0+2056);   F3 = ldf4(zp0+2060);
        } else if (kg == 2) {
            O0 = ldf4(zp0+4096);   O1 = ldf4(zp0+4100);   O2 = ldf4(zp0+4104);   O3 = ldf4(zp0+4108);
            G0 = ldf4(zp0+6144);   G1 = ldf4(zp0+6148);   G2 = ldf4(zp0+6152);   G3 = ldf4(zp0+6156);
        }
#pragma unroll
        for (int j = 0; j < 8; ++j)
            ROW16(&hp[(kg * 8 + j) * RS + 4 + f0], Wv[j][0], Wv[j][1], Wv[j][2]);

        if (kg > 0) {
            float* zp;
            zp = &zs[(((kg-1)*4 + 0)*32 + ch)*68 + f0];
            stf4(zp, I0); stf4(zp+4, I1); stf4(zp+8, I2); stf4(zp+12, I3);
            zp = &zs[(((kg-1)*4 + 1)*32 + ch)*68 + f0];
            stf4(zp, F0); stf4(zp+4, F1); stf4(zp+8, F2); stf4(zp+12, F3);
            zp = &zs[(((kg-1)*4 + 2)*32 + ch)*68 + f0];
            stf4(zp, O0); stf4(zp+4, O1); stf4(zp+8, O2); stf4(zp+12, O3);
            zp = &zs[(((kg-1)*4 + 3)*32 + ch)*68 + f0];
            stf4(zp, G0); stf4(zp+4, G1); stf4(zp+8, G2); stf4(zp+12, G3);
        }
        __syncthreads();                                       // A
        if (kg == 0) {
            const float bi = bs[ch], bf = bs[32+ch], bo = bs[64+ch], bg = bs[96+ch];
            float* seqp = &seq[((size_t)t * B_ + b) * 2048 + ch * 64 + f0];
#define DZP(k,g) (&zs[(((k)*4+(g))*32 + ch)*68 + f0])
#define DQ(q, AI,AF,AO,AG) { \
    float4 zi = r3(AI, DZP(0,0)+4*q, DZP(1,0)+4*q, DZP(2,0)+4*q); \
    float4 zf = r3(AF, DZP(0,1)+4*q, DZP(1,1)+4*q, DZP(2,1)+4*q); \
    float4 zo = r3(AO, DZP(0,2)+4*q, DZP(1,2)+4*q, DZP(2,2)+4*q); \
    float4 zg = r3(AG, DZP(0,3)+4*q, DZP(1,3)+4*q, DZP(2,3)+4*q); \
    float4 cq = ldf4(&cb[ch*68 + f0 + 4*q]); \
    float4 hq = gate4(zi,zf,zo,zg, bi,bf,bo,bg, cq); \
    stf4(&cb[ch*68 + f0 + 4*q], cq); \
    stf4(&hp[ch*RS + 4 + f0 + 4*q], hq); \
    stf4(seqp + 4*q, hq); }
            DQ(0, I0, F0, O0, G0)
            DQ(1, I1, F1, O1, G1)
            DQ(2, I2, F2, O2, G2)
            DQ(3, I3, F3, O3, G3)
#undef DQ
#undef DZP
        }
        __syncthreads();                                       // B
    }

    for (int i = tid; i < 2048; i += 512) {
        int c8 = i >> 6, f = i & 63;
        hout[b * 2048 + i] = hp[c8 * RS + 4 + f];
        cout[b * 2048 + i] = cb[c8 * 68 + f];
    }
}

// ---------------------------------------------------------------------------
// dec1k: decoder L1 recurrence (h-part only) + final 1x1 conv.
// (16h)->16, FT=8, kg-split. 2 barriers/step.
// ---------------------------------------------------------------------------
__global__ __launch_bounds__(512, 2) void dec1k(
    const float* __restrict__ w, const float* __restrict__ bias,
    const float* __restrict__ zx,
    const float* __restrict__ hin, const float* __restrict__ cin,
    float* __restrict__ hout, float* __restrict__ cout,
    const float* __restrict__ fw, const float* __restrict__ fb,
    float* __restrict__ out, int t0, int tn)
{
    __shared__ float hp[16 * RS];
    __shared__ float cb[16 * 68];
    __shared__ float zs[3 * 4 * 16 * 68];
    __shared__ float bs[64];
    __shared__ float fcw[16];
    __shared__ float fcb;

    const int tid = threadIdx.x, b = blockIdx.x;
    const int kg = tid >> 7, ch = tid & 15, f0 = ((tid >> 4) & 7) * 8;

    float4 Wv[4][3];
#pragma unroll
    for (int j = 0; j < 4; ++j) {
        int ci = 32 + kg * 4 + j;
#pragma unroll
        for (int d = 0; d < 3; ++d)
            Wv[j][d] = make_float4(
                w[((0 * 16 + ch) * 48 + ci) * 9 + d * 3 + 1],
                w[((1 * 16 + ch) * 48 + ci) * 9 + d * 3 + 1],
                w[((2 * 16 + ch) * 48 + ci) * 9 + d * 3 + 1],
                w[((3 * 16 + ch) * 48 + ci) * 9 + d * 3 + 1]);
    }
    if (tid < 64) bs[tid] = bias[tid];
    if (tid < 16) fcw[tid] = fw[tid];
    if (tid == 16) fcb = fb[0];
    for (int i = tid; i < 16 * RS; i += 512) hp[i] = 0.f;
    __syncthreads();
    for (int i = tid; i < 1024; i += 512) {
        int c8 = i >> 6, f = i & 63;
        hp[c8 * RS + 4 + f] = hin[b * 1024 + i];
        cb[c8 * 68 + f] = cin[b * 1024 + i];
    }
    __syncthreads();

    const float4 z4 = make_float4(0.f, 0.f, 0.f, 0.f);

#pragma unroll 1
    for (int tl = 0; tl < tn; ++tl) {
        const int t = t0 + tl;
        float4 I0=z4,I1=z4,F0=z4,F1=z4,O0=z4,O1=z4,G0=z4,G1=z4;
        const float* zp0 = &zx[((size_t)tl * B_ + b) * 4096 + ch * 64 + f0];
        if (kg == 1) {
            I0 = ldf4(zp0);        I1 = ldf4(zp0+4);
            F0 = ldf4(zp0+1024);   F1 = ldf4(zp0+1028);
        } else if (kg == 2) {
            O0 = ldf4(zp0+2048);   O1 = ldf4(zp0+2052);
            G0 = ldf4(zp0+3072);   G1 = ldf4(zp0+3076);
        }
#pragma unroll
        for (int j = 0; j < 4; ++j)
            ROW8(&hp[(kg * 4 + j) * RS + 4 + f0], Wv[j][0], Wv[j][1], Wv[j][2]);

        if (kg > 0) {
            float* zp;
            zp = &zs[(((kg-1)*4 + 0)*16 + ch)*68 + f0]; stf4(zp, I0); stf4(zp+4, I1);
            zp = &zs[(((kg-1)*4 + 1)*16 + ch)*68 + f0]; stf4(zp, F0); stf4(zp+4, F1);
            zp = &zs[(((kg-1)*4 + 2)*16 + ch)*68 + f0]; stf4(zp, O0); stf4(zp+4, O1);
            zp = &zs[(((kg-1)*4 + 3)*16 + ch)*68 + f0]; stf4(zp, G0); stf4(zp+4, G1);
        }
        __syncthreads();                                       // A
        if (kg == 0) {
            const float bi = bs[ch], bf = bs[16+ch], bo = bs[32+ch], bg = bs[48+ch];
#define TZP(k,g) (&zs[(((k)*4+(g))*16 + ch)*68 + f0])
#define TQ(q, AI,AF,AO,AG) { \
    float4 zi = r3(AI, TZP(0,0)+4*q, TZP(1,0)+4*q, TZP(2,0)+4*q); \
    float4 zf = r3(AF, TZP(0,1)+4*q, TZP(1,1)+4*q, TZP(2,1)+4*q); \
    float4 zo = r3(AO, TZP(0,2)+4*q, TZP(1,2)+4*q, TZP(2,2)+4*q); \
    float4 zg = r3(AG, TZP(0,3)+4*q, TZP(1,3)+4*q, TZP(2,3)+4*q); \
    float4 cq = ldf4(&cb[ch*68 + f0 + 4*q]); \
    float4 hq = gate4(zi,zf,zo,zg, bi,bf,bo,bg, cq); \
    stf4(&cb[ch*68 + f0 + 4*q], cq); \
    stf4(&hp[ch*RS + 4 + f0 + 4*q], hq); }
            TQ(0, I0, F0, O0, G0)
            TQ(1, I1, F1, O1, G1)
#undef TQ
#undef TZP
        }
        __syncthreads();                                       // B
        if (tid < 64) {
            float a = fcb;
#pragma unroll
            for (int k2 = 0; k2 < 16; ++k2)
                a = fmaf(fcw[k2], hp[k2 * RS + 4 + tid], a);
            out[(b * T_ + t) * 64 + tid] = a;
        }
    }

    for (int i = tid; i < 1024; i += 512) {
        int c8 = i >> 6, f = i & 63;
        hout[b * 1024 + i] = hp[c8 * RS + 4 + f];
        cout[b * 1024 + i] = cb[c8 * 68 + f];
    }
}

// ---------------------------------------------------------------------------
// Fallback (ws too small for zx): fused x+h decoders, round-4 structure.
// ---------------------------------------------------------------------------
__global__ __launch_bounds__(512, 2) void dec0_fb(
    const float* __restrict__ w, const float* __restrict__ bias,
    float* __restrict__ seq,
    const float* __restrict__ hin, const float* __restrict__ cin)
{
    __shared__ float wl[192 * 128];
    __shared__ float bs[128];
    __shared__ float xin[32 * RS];
    __shared__ float hp[32 * RS];

    const int tid = threadIdx.x;
    const int b = blockIdx.x;

    for (int idx = tid; idx < 192 * 128; idx += 512) {
        int k = idx >> 7, r = idx & 127;
        int ch = r >> 2, g = r & 3;
        int ci = k / 3, d = k - ci * 3;
        wl[idx] = w[((g * 32 + ch) * 64 + ci) * 9 + d * 3 + 1];
    }
    if (tid < 128) bs[tid] = bias[tid];
    for (int i = tid; i < 32 * RS; i += 512) { xin[i] = 0.f; hp[i] = 0.f; }
    __syncthreads();
    {
        const float* hs = &hin[b * 2048 + tid * 4];
        float4 hv = ldf4(hs);
        int ci = tid >> 4, col = (tid & 15) * 4;
        stf4(&hp[ci * RS + 4 + col], hv);
    }
    const int ch = tid >> 4, f0 = (tid & 15) * 4;
    float4 cc = ldf4(&cin[b * 2048 + ch * 64 + f0]);
    const float bi = bs[ch], bf = bs[32 + ch], bo = bs[64 + ch], bg = bs[96 + ch];
    const float4 z4 = make_float4(0.f,0.f,0.f,0.f);

    float4 nx = ldf4(&seq[(size_t)b * 2048 + tid * 4]);

#pragma unroll 1
    for (int t = 0; t < T_; ++t) {
        {
            int ci = tid >> 4, col = (tid & 15) * 4;
            stf4(&xin[ci * RS + 4 + col], nx);
        }
        __syncthreads();
        if (t + 1 < T_)
            nx = ldf4(&seq[((size_t)(t + 1) * B_ + b) * 2048 + tid * 4]);
        float4 ai = z4, af = z4, ao = z4, ag = z4;
#pragma unroll 1
        for (int r = 0; r < 32; ++r)
            rowacc4<128>(&xin[r * RS + 4 + f0], wl + (r * 3) * 128 + ch * 4, ai, af, ao, ag);
#pragma unroll 1
        for (int r = 0; r < 32; ++r)
            rowacc4<128>(&hp[r * RS + 4 + f0], wl + ((32 + r) * 3) * 128 + ch * 4, ai, af, ao, ag);
        float4 hn = gate4(ai, af, ao, ag, bi, bf, bo, bg, cc);
        __syncthreads();
        stf4(&hp[ch * RS + 4 + f0], hn);
        stf4(&seq[((size_t)t * B_ + b) * 2048 + ch * 64 + f0], hn);
    }
}

__global__ __launch_bounds__(512, 2) void dec1_fb(
    const float* __restrict__ w, const float* __restrict__ bias,
    const float* __restrict__ seq,
    const float* __restrict__ hin, const float* __restrict__ cin,
    const float* __restrict__ fw, const float* __restrict__ fb,
    float* __restrict__ out)
{
    __shared__ float wl[144 * 64];
    __shared__ float bs[64];
    __shared__ float xin[32 * RS];
    __shared__ float hp[16 * RS];
    __shared__ float fcw[16];
    __shared__ float fcb;

    const int tid = threadIdx.x;
    const int b = blockIdx.x;

    for (int idx = tid; idx < 144 * 64; idx += 512) {
        int k = idx >> 6, r = idx & 63;
        int ch = r >> 2, g = r & 3;
        int ci = k / 3, d = k - ci * 3;
        wl[idx] = w[((g * 16 + ch) * 48 + ci) * 9 + d * 3 + 1];
    }
    if (tid < 64) bs[tid] = bias[tid];
    if (tid < 16) fcw[tid] = fw[tid];
    if (tid == 16) fcb = fb[0];
    for (int i = tid; i < 32 * RS; i += 512) xin[i] = 0.f;
    for (int i = tid; i < 16 * RS; i += 512) hp[i] = 0.f;
    __syncthreads();
    {
        const float* hs = &hin[b * 1024 + tid * 2];
        float2 hv = *reinterpret_cast<const float2*>(hs);
        int ci = tid >> 5, col = (tid & 31) * 2;
        *reinterpret_cast<float2*>(&hp[ci * RS + 4 + col]) = hv;
    }
    const int ch = tid >> 5, f0 = (tid & 31) * 2;
    float2 cc = *reinterpret_cast<const float2*>(&cin[b * 1024 + ch * 64 + f0]);
    const float bi = bs[ch], bf = bs[16 + ch], bo = bs[32 + ch], bg = bs[48 + ch];
    const float2 z2 = make_float2(0.f,0.f);
    float4 nx = ldf4(&seq[(size_t)b * 2048 + tid * 4]);
    __syncthreads();

#pragma unroll 1
    for (int t = 0; t < T_; ++t) {
        {
            int ci = tid >> 4, col = (tid & 15) * 4;
            stf4(&xin[ci * RS + 4 + col], nx);
        }
        __syncthreads();
        if (t + 1 < T_)
            nx = ldf4(&seq[((size_t)(t + 1) * B_ + b) * 2048 + tid * 4]);

        float2 ai = z2, af = z2, ao = z2, ag = z2;
#pragma unroll 1
        for (int r = 0; r < 32; ++r)
            rowacc2<64>(&xin[r * RS + 4 + f0], wl + (r * 3) * 64 + ch * 4, ai, af, ao, ag);
#pragma unroll 1
        for (int r = 0; r < 16; ++r)
            rowacc2<64>(&hp[r * RS + 4 + f0], wl + ((32 + r) * 3) * 64 + ch * 4, ai, af, ao, ag);

        float2 hh;
        hh.x = gate1(ai.x + bi, af.x + bf, ao.x + bo, ag.x + bg, cc.x);
        hh.y = gate1(ai.y + bi, af.y + bf, ao.y + bo, ag.y + bg, cc.y);
        __syncthreads();
        *reinterpret_cast<float2*>(&hp[ch * RS + 4 + f0]) = hh;
        __syncthreads();

        if (tid < 64) {
            float a = fcb;
#pragma unroll
            for (int k2 = 0; k2 < 16; ++k2)
                a = fmaf(fcw[k2], hp[k2 * RS + 4 + tid], a);
            out[(b * T_ + t) * 64 + tid] = a;
        }
    }
}

// ---------------------------------------------------------------------------
extern "C" void kernel_launch(void* const* d_in, const int* in_sizes, int n_in,
                              void* d_out, int out_size, void* d_ws, size_t ws_size,
                              hipStream_t stream)
{
    (void)in_sizes; (void)n_in; (void)out_size;
    const float* x   = (const float*)d_in[0];
    const float* ew0 = (const float*)d_in[1];
    const float* eb0 = (const float*)d_in[2];
    const float* ew1 = (const float*)d_in[3];
    const float* eb1 = (const float*)d_in[4];
    const float* dw0 = (const float*)d_in[5];
    const float* db0 = (const float*)d_in[6];
    const float* dw1 = (const float*)d_in[7];
    const float* db1 = (const float*)d_in[8];
    const float* fw  = (const float*)d_in[9];
    const float* fb  = (const float*)d_in[10];
    float* out = (float*)d_out;

    float* ws  = (float*)d_ws;
    size_t off = 0;
    float* seq = ws + off; off += (size_t)T_ * B_ * 2048;
    float* h1f = ws + off; off += (size_t)B_ * 1024;
    float* c1f = ws + off; off += (size_t)B_ * 1024;
    float* h2f = ws + off; off += (size_t)B_ * 2048;
    float* c2f = ws + off; off += (size_t)B_ * 2048;
    float* hd0 = ws + off; off += (size_t)B_ * 2048;
    float* cd0 = ws + off; off += (size_t)B_ * 2048;
    float* hd1 = ws + off; off += (size_t)B_ * 1024;
    float* cd1 = ws + off; off += (size_t)B_ * 1024;
    float* zx  = ws + off;

    size_t availf = (ws_size / 4 > off) ? (ws_size / 4 - off) : 0;
    int TC = 0;
    if      (availf >= (size_t)100 * B_ * 8192) TC = 100;
    else if (availf >= (size_t)50  * B_ * 8192) TC = 50;
    else if (availf >= (size_t)25  * B_ * 8192) TC = 25;
    else if (availf >= (size_t)10  * B_ * 8192) TC = 10;

    enc_kernel<<<B_, 512, 0, stream>>>(x, ew0, eb0, ew1, eb1, seq, h1f, c1f, h2f, c2f);

    if (TC > 0) {
        for (int t0 = 0; t0 < T_; t0 += TC) {
            xconv0_kernel<<<TC * B_, 256, 0, stream>>>(seq, dw0, zx, t0);
            dec0k<<<B_, 512, 0, stream>>>(
                dw0, db0, seq, zx,
                t0 == 0 ? h2f : hd0, t0 == 0 ? c2f : cd0, hd0, cd0, t0, TC);
        }
        for (int t0 = 0; t0 < T_; t0 += TC) {
            xconv1_kernel<<<TC * B_, 256, 0, stream>>>(seq, dw1, zx, t0);
            dec1k<<<B_, 512, 0, stream>>>(
                dw1, db1, zx,
                t0 == 0 ? h1f : hd1, t0 == 0 ? c1f : cd1, hd1, cd1,
                fw, fb, out, t0, TC);
        }
    } else {
        dec0_fb<<<B_, 512, 0, stream>>>(dw0, db0, seq, h2f, c2f);
        dec1_fb<<<B_, 512, 0, stream>>>(dw1, db1, seq, h1f, c1f, fw, fb, out);
    }
}

// Round 6
// 14297.563 us; speedup vs baseline: 1.0018x; 1.0018x over previous
//
#include <hip/hip_runtime.h>
#include <math.h>

#define B_ 128
#define T_ 100
#define RS 72      // padded row stride (words); data cols [4..67]; [0..3],[68..71] zero

// ---------------------------------------------------------------------------
// Fast transcendentals (~1e-6 rel err; threshold 1.27e-4)
// ---------------------------------------------------------------------------
__device__ __forceinline__ float frcp_(float x){ return __builtin_amdgcn_rcpf(x); }
__device__ __forceinline__ float fsig_(float x){ return frcp_(1.f + __expf(-x)); }
__device__ __forceinline__ float ftanh_(float x){ float e = __expf(2.f*x); return 1.f - 2.f*frcp_(e+1.f); }
__device__ __forceinline__ float gate1(float zi, float zf, float zo, float zg, float& c){
    float cc = fsig_(zf)*c + fsig_(zi)*ftanh_(zg);
    c = cc;
    return fsig_(zo)*ftanh_(cc);
}
__device__ __forceinline__ float4 ldf4(const float* p){ return *reinterpret_cast<const float4*>(p); }
__device__ __forceinline__ void stf4(float* p, float4 v){ *reinterpret_cast<float4*>(p) = v; }
__device__ __forceinline__ float4 r3(float4 o, const float* a, const float* b, const float* c){
    float4 x = ldf4(a), y = ldf4(b), z = ldf4(c);
    return make_float4(o.x+x.x+y.x+z.x, o.y+x.y+y.y+z.y,
                       o.z+x.z+y.z+z.z, o.w+x.w+y.w+z.w);
}
__device__ __forceinline__ float4 gate4(float4 zi, float4 zf, float4 zo, float4 zg,
                                        float bi, float bf, float bo, float bg, float4& c){
    float4 h;
    h.x = gate1(zi.x+bi, zf.x+bf, zo.x+bo, zg.x+bg, c.x);
    h.y = gate1(zi.y+bi, zf.y+bf, zo.y+bo, zg.y+bg, c.y);
    h.z = gate1(zi.z+bi, zf.z+bf, zo.z+bo, zg.z+bg, c.z);
    h.w = gate1(zi.w+bi, zf.w+bf, zo.w+bo, zg.w+bg, c.w);
    return h;
}

// 4 gates x 4 columns FMA: W = float4 of gate weights (i,f,o,g), u0..u3 = data
#define FMAQ(W, u0,u1,u2,u3, QI,QF,QO,QG) do{\
  QI.x=fmaf(W.x,u0,QI.x); QI.y=fmaf(W.x,u1,QI.y); QI.z=fmaf(W.x,u2,QI.z); QI.w=fmaf(W.x,u3,QI.w);\
  QF.x=fmaf(W.y,u0,QF.x); QF.y=fmaf(W.y,u1,QF.y); QF.z=fmaf(W.y,u2,QF.z); QF.w=fmaf(W.y,u3,QF.w);\
  QO.x=fmaf(W.z,u0,QO.x); QO.y=fmaf(W.z,u1,QO.y); QO.z=fmaf(W.z,u2,QO.z); QO.w=fmaf(W.z,u3,QO.w);\
  QG.x=fmaf(W.w,u0,QG.x); QG.y=fmaf(W.w,u1,QG.y); QG.z=fmaf(W.w,u2,QG.z); QG.w=fmaf(W.w,u3,QG.w);\
}while(0)

// One row, 16 output columns, all 4 gates. Acc names I0..I3,F0..F3,O0..O3,G0..G3.
#define ROW16(RP, W0, W1, W2) do{ \
  const float* rp_ = (RP); \
  float m_ = rp_[-1]; \
  float4 A_ = ldf4(rp_); float4 Bq_ = ldf4(rp_+4); \
  float4 Cq_ = ldf4(rp_+8); float4 Dq_ = ldf4(rp_+12); \
  float p_ = rp_[16]; \
  FMAQ(W1, A_.x,A_.y,A_.z,A_.w,     I0,F0,O0,G0); \
  FMAQ(W1, Bq_.x,Bq_.y,Bq_.z,Bq_.w, I1,F1,O1,G1); \
  FMAQ(W1, Cq_.x,Cq_.y,Cq_.z,Cq_.w, I2,F2,O2,G2); \
  FMAQ(W1, Dq_.x,Dq_.y,Dq_.z,Dq_.w, I3,F3,O3,G3); \
  FMAQ(W0, m_,A_.x,A_.y,A_.z,       I0,F0,O0,G0); \
  FMAQ(W0, A_.w,Bq_.x,Bq_.y,Bq_.z,  I1,F1,O1,G1); \
  FMAQ(W0, Bq_.w,Cq_.x,Cq_.y,Cq_.z, I2,F2,O2,G2); \
  FMAQ(W0, Cq_.w,Dq_.x,Dq_.y,Dq_.z, I3,F3,O3,G3); \
  FMAQ(W2, A_.y,A_.z,A_.w,Bq_.x,    I0,F0,O0,G0); \
  FMAQ(W2, Bq_.y,Bq_.z,Bq_.w,Cq_.x, I1,F1,O1,G1); \
  FMAQ(W2, Cq_.y,Cq_.z,Cq_.w,Dq_.x, I2,F2,O2,G2); \
  FMAQ(W2, Dq_.y,Dq_.z,Dq_.w,p_,    I3,F3,O3,G3); \
}while(0)

// One row, 8 output columns. Acc names I0,I1,F0,F1,O0,O1,G0,G1.
#define ROW8(RP, W0, W1, W2) do{ \
  const float* rp_ = (RP); \
  float m_ = rp_[-1]; \
  float4 A_ = ldf4(rp_); float4 Bq_ = ldf4(rp_+4); \
  float p_ = rp_[8]; \
  FMAQ(W1, A_.x,A_.y,A_.z,A_.w,     I0,F0,O0,G0); \
  FMAQ(W1, Bq_.x,Bq_.y,Bq_.z,Bq_.w, I1,F1,O1,G1); \
  FMAQ(W0, m_,A_.x,A_.y,A_.z,       I0,F0,O0,G0); \
  FMAQ(W0, A_.w,Bq_.x,Bq_.y,Bq_.z,  I1,F1,O1,G1); \
  FMAQ(W2, A_.y,A_.z,A_.w,Bq_.x,    I0,F0,O0,G0); \
  FMAQ(W2, Bq_.y,Bq_.z,Bq_.w,p_,    I1,F1,O1,G1); \
}while(0)

// ---------------------------------------------------------------------------
// Helpers for xconv + fallback kernels
// ---------------------------------------------------------------------------
__device__ __forceinline__ void fma4v(float w, float u0,float u1,float u2,float u3, float4& a){
    a.x = fmaf(w,u0,a.x); a.y = fmaf(w,u1,a.y);
    a.z = fmaf(w,u2,a.z); a.w = fmaf(w,u3,a.w);
}
__device__ __forceinline__ void fma2v(float w, float u0,float u1, float2& a){
    a.x = fmaf(w,u0,a.x); a.y = fmaf(w,u1,a.y);
}
template<int ROWS>
__device__ __forceinline__ void rowacc4(const float* __restrict__ rowp,
                                        const float* __restrict__ wk,
                                        float4& ai, float4& af, float4& ao, float4& ag)
{
    float  m = rowp[-1];
    float4 a = ldf4(rowp);
    float  p = rowp[4];
    float4 wa = ldf4(wk);
    float4 wb = ldf4(wk + ROWS);
    float4 wc = ldf4(wk + 2*ROWS);
    fma4v(wa.x, m,a.x,a.y,a.z, ai);  fma4v(wa.y, m,a.x,a.y,a.z, af);
    fma4v(wa.z, m,a.x,a.y,a.z, ao);  fma4v(wa.w, m,a.x,a.y,a.z, ag);
    fma4v(wb.x, a.x,a.y,a.z,a.w, ai); fma4v(wb.y, a.x,a.y,a.z,a.w, af);
    fma4v(wb.z, a.x,a.y,a.z,a.w, ao); fma4v(wb.w, a.x,a.y,a.z,a.w, ag);
    fma4v(wc.x, a.y,a.z,a.w,p, ai);  fma4v(wc.y, a.y,a.z,a.w,p, af);
    fma4v(wc.z, a.y,a.z,a.w,p, ao);  fma4v(wc.w, a.y,a.z,a.w,p, ag);
}
template<int ROWS>
__device__ __forceinline__ void rowacc2(const float* __restrict__ rowp,
                                        const float* __restrict__ wk,
                                        float2& ai, float2& af, float2& ao, float2& ag)
{
    float  m = rowp[-1];
    float2 a = *reinterpret_cast<const float2*>(rowp);
    float  p = rowp[2];
    float4 wa = ldf4(wk);
    float4 wb = ldf4(wk + ROWS);
    float4 wc = ldf4(wk + 2*ROWS);
    fma2v(wa.x, m,a.x, ai); fma2v(wa.y, m,a.x, af);
    fma2v(wa.z, m,a.x, ao); fma2v(wa.w, m,a.x, ag);
    fma2v(wb.x, a.x,a.y, ai); fma2v(wb.y, a.x,a.y, af);
    fma2v(wb.z, a.x,a.y, ao); fma2v(wb.w, a.x,a.y, ag);
    fma2v(wc.x, a.y,p, ai); fma2v(wc.y, a.y,p, af);
    fma2v(wc.z, a.y,p, ao); fma2v(wc.w, a.y,p, ag);
}
template<int ROWS>
__device__ __forceinline__ void rowacc8(const float* __restrict__ rowp,
                                        const float* __restrict__ wk,
                                        float4& i0, float4& i1, float4& f0v, float4& f1v,
                                        float4& o0, float4& o1, float4& g0, float4& g1)
{
    float  m = rowp[-1];
    float4 a = ldf4(rowp);
    float4 b = ldf4(rowp + 4);
    float  p = rowp[8];
    float4 wa = ldf4(wk);
    float4 wb = ldf4(wk + ROWS);
    float4 wc = ldf4(wk + 2*ROWS);
    fma4v(wa.x, m,a.x,a.y,a.z, i0);   fma4v(wa.x, a.w,b.x,b.y,b.z, i1);
    fma4v(wa.y, m,a.x,a.y,a.z, f0v);  fma4v(wa.y, a.w,b.x,b.y,b.z, f1v);
    fma4v(wa.z, m,a.x,a.y,a.z, o0);   fma4v(wa.z, a.w,b.x,b.y,b.z, o1);
    fma4v(wa.w, m,a.x,a.y,a.z, g0);   fma4v(wa.w, a.w,b.x,b.y,b.z, g1);
    fma4v(wb.x, a.x,a.y,a.z,a.w, i0); fma4v(wb.x, b.x,b.y,b.z,b.w, i1);
    fma4v(wb.y, a.x,a.y,a.z,a.w, f0v);fma4v(wb.y, b.x,b.y,b.z,b.w, f1v);
    fma4v(wb.z, a.x,a.y,a.z,a.w, o0); fma4v(wb.z, b.x,b.y,b.z,b.w, o1);
    fma4v(wb.w, a.x,a.y,a.z,a.w, g0); fma4v(wb.w, b.x,b.y,b.z,b.w, g1);
    fma4v(wc.x, a.y,a.z,a.w,b.x, i0); fma4v(wc.x, b.y,b.z,b.w,p, i1);
    fma4v(wc.y, a.y,a.z,a.w,b.x, f0v);fma4v(wc.y, b.y,b.z,b.w,p, f1v);
    fma4v(wc.z, a.y,a.z,a.w,b.x, o0); fma4v(wc.z, b.y,b.z,b.w,p, o1);
    fma4v(wc.w, a.y,a.z,a.w,b.x, g0); fma4v(wc.w, b.y,b.z,b.w,p, g1);
}

// ---------------------------------------------------------------------------
// Encoder: kg-split over K, L1 weights in VGPR, partial-z reduction via LDS.
// L0: (1+16)->16, FT=8; L1: (16+32)->32, FT=16. 512 threads, 4 barriers/step.
// __launch_bounds__(512,1): 8 waves need <=256 VGPR each (Wv=144 + acc=64 +
// temps ~= 240); LDS (146KB) limits to 1 block/CU regardless. (512,2) capped
// VGPRs at 128 and spilled Wv to scratch -> 15 GB/dispatch HBM traffic (r5).
// ---------------------------------------------------------------------------
__global__ __launch_bounds__(512, 1) void enc_kernel(
    const float* __restrict__ x,
    const float* __restrict__ w0, const float* __restrict__ b0,
    const float* __restrict__ w1, const float* __restrict__ b1,
    float* __restrict__ seq,
    float* __restrict__ h1f, float* __restrict__ c1f,
    float* __restrict__ h2f, float* __restrict__ c2f)
{
    __shared__ float wl0[51 * 64];
    __shared__ float bs0[64];
    __shared__ float bs1[128];
    __shared__ float hbuf[49 * RS];
    __shared__ float cb0[16 * 68];
    __shared__ float cb1[32 * 68];
    __shared__ float zs[3 * 4 * 32 * 68];

    const int tid = threadIdx.x;
    const int b = blockIdx.x;
    const int kg = tid >> 7;
    const int chA = tid & 15, f0A = ((tid >> 4) & 7) * 8;
    const int chB = tid & 31, f0B = ((tid >> 5) & 3) * 16;

    // L1 weights into registers: Wv[j][d] = gates(i,f,o,g) for row ci=kg*12+j, tap d
    float4 Wv[12][3];
#pragma unroll
    for (int j = 0; j < 12; ++j) {
        int ci = kg * 12 + j;
#pragma unroll
        for (int d = 0; d < 3; ++d) {
            Wv[j][d] = make_float4(
                w1[((0 * 32 + chB) * 48 + ci) * 9 + d * 3 + 1],
                w1[((1 * 32 + chB) * 48 + ci) * 9 + d * 3 + 1],
                w1[((2 * 32 + chB) * 48 + ci) * 9 + d * 3 + 1],
                w1[((3 * 32 + chB) * 48 + ci) * 9 + d * 3 + 1]);
        }
    }
    for (int idx = tid; idx < 51 * 64; idx += 512) {
        int k = idx >> 6, r = idx & 63;
        int ch = r >> 2, g = r & 3;
        int ci = k / 3, d = k - ci * 3;
        wl0[idx] = w0[((g * 16 + ch) * 17 + ci) * 9 + d * 3 + 1];
    }
    if (tid < 64) bs0[tid] = b0[tid];
    if (tid < 128) bs1[tid] = b1[tid];
    for (int i = tid; i < 49 * RS; i += 512) hbuf[i] = 0.f;
    for (int i = tid; i < 16 * 68; i += 512) cb0[i] = 0.f;
    for (int i = tid; i < 32 * 68; i += 512) cb1[i] = 0.f;
    __syncthreads();

    const int xl = tid - 384;       // wave 6 stages x
    float xv = 0.f;
    if (kg == 3 && xl >= 0 && xl < 64) {
        hbuf[4 + xl] = x[(b * T_ + 0) * 64 + xl];
        if (T_ > 1) xv = x[(b * T_ + 1) * 64 + xl];
    }
    __syncthreads();

    const float4 z4 = make_float4(0.f, 0.f, 0.f, 0.f);

#pragma unroll 1
    for (int t = 0; t < T_; ++t) {
        // ================= layer 0 =================
        {
            float4 I0=z4,I1=z4,F0=z4,F1=z4,O0=z4,O1=z4,G0=z4,G1=z4;
            if (kg == 0) {   // x row (ci=0), wave-uniform branch
                float4 W0 = ldf4(&wl0[0 * 64 + chA * 4]);
                float4 W1 = ldf4(&wl0[1 * 64 + chA * 4]);
                float4 W2 = ldf4(&wl0[2 * 64 + chA * 4]);
                ROW8(&hbuf[4 + f0A], W0, W1, W2);
            }
#pragma unroll
            for (int j = 0; j < 4; ++j) {
                int ci = 1 + kg * 4 + j;
                float4 W0 = ldf4(&wl0[(ci * 3 + 0) * 64 + chA * 4]);
                float4 W1 = ldf4(&wl0[(ci * 3 + 1) * 64 + chA * 4]);
                float4 W2 = ldf4(&wl0[(ci * 3 + 2) * 64 + chA * 4]);
                ROW8(&hbuf[ci * RS + 4 + f0A], W0, W1, W2);
            }
            if (kg > 0) {
                float* zp;
                zp = &zs[(((kg-1)*4 + 0)*16 + chA)*68 + f0A]; stf4(zp, I0); stf4(zp+4, I1);
                zp = &zs[(((kg-1)*4 + 1)*16 + chA)*68 + f0A]; stf4(zp, F0); stf4(zp+4, F1);
                zp = &zs[(((kg-1)*4 + 2)*16 + chA)*68 + f0A]; stf4(zp, O0); stf4(zp+4, O1);
                zp = &zs[(((kg-1)*4 + 3)*16 + chA)*68 + f0A]; stf4(zp, G0); stf4(zp+4, G1);
            }
            __syncthreads();                                   // A
            if (kg == 0) {
                const float bi = bs0[chA], bf = bs0[16+chA], bo = bs0[32+chA], bg = bs0[48+chA];
#define AZP(k,g) (&zs[(((k)*4+(g))*16 + chA)*68 + f0A])
#define AQ(q, AI,AF,AO,AG) { \
    float4 zi = r3(AI, AZP(0,0)+4*q, AZP(1,0)+4*q, AZP(2,0)+4*q); \
    float4 zf = r3(AF, AZP(0,1)+4*q, AZP(1,1)+4*q, AZP(2,1)+4*q); \
    float4 zo = r3(AO, AZP(0,2)+4*q, AZP(1,2)+4*q, AZP(2,2)+4*q); \
    float4 zg = r3(AG, AZP(0,3)+4*q, AZP(1,3)+4*q, AZP(2,3)+4*q); \
    float4 cq = ldf4(&cb0[chA*68 + f0A + 4*q]); \
    float4 hq = gate4(zi,zf,zo,zg, bi,bf,bo,bg, cq); \
    stf4(&cb0[chA*68 + f0A + 4*q], cq); \
    stf4(&hbuf[(1+chA)*RS + 4 + f0A + 4*q], hq); }
                AQ(0, I0, F0, O0, G0)
                AQ(1, I1, F1, O1, G1)
#undef AQ
#undef AZP
            }
            __syncthreads();                                   // B
        }
        // ================= layer 1 =================
        {
            float4 I0=z4,I1=z4,I2=z4,I3=z4,F0=z4,F1=z4,F2=z4,F3=z4;
            float4 O0=z4,O1=z4,O2=z4,O3=z4,G0=z4,G1=z4,G2=z4,G3=z4;
#pragma unroll
            for (int j = 0; j < 12; ++j)
                ROW16(&hbuf[(1 + kg*12 + j)*RS + 4 + f0B], Wv[j][0], Wv[j][1], Wv[j][2]);

            if (kg > 0) {
                float* zp;
                zp = &zs[(((kg-1)*4 + 0)*32 + chB)*68 + f0B];
                stf4(zp, I0); stf4(zp+4, I1); stf4(zp+8, I2); stf4(zp+12, I3);
                zp = &zs[(((kg-1)*4 + 1)*32 + chB)*68 + f0B];
                stf4(zp, F0); stf4(zp+4, F1); stf4(zp+8, F2); stf4(zp+12, F3);
                zp = &zs[(((kg-1)*4 + 2)*32 + chB)*68 + f0B];
                stf4(zp, O0); stf4(zp+4, O1); stf4(zp+8, O2); stf4(zp+12, O3);
                zp = &zs[(((kg-1)*4 + 3)*32 + chB)*68 + f0B];
                stf4(zp, G0); stf4(zp+4, G1); stf4(zp+8, G2); stf4(zp+12, G3);
            }
            if (kg == 3 && xl >= 0 && xl < 64) {   // stage x(t+1) into row 0
                hbuf[4 + xl] = xv;
                if (t + 2 < T_) xv = x[(b * T_ + t + 2) * 64 + xl];
            }
            __syncthreads();                                   // C
            if (kg == 0) {
                const float bi = bs1[chB], bf = bs1[32+chB], bo = bs1[64+chB], bg = bs1[96+chB];
                float* seqp = &seq[((size_t)t * B_ + b) * 2048 + chB * 64 + f0B];
#define EZP(k,g) (&zs[(((k)*4+(g))*32 + chB)*68 + f0B])
#define EQ(q, AI,AF,AO,AG) { \
    float4 zi = r3(AI, EZP(0,0)+4*q, EZP(1,0)+4*q, EZP(2,0)+4*q); \
    float4 zf = r3(AF, EZP(0,1)+4*q, EZP(1,1)+4*q, EZP(2,1)+4*q); \
    float4 zo = r3(AO, EZP(0,2)+4*q, EZP(1,2)+4*q, EZP(2,2)+4*q); \
    float4 zg = r3(AG, EZP(0,3)+4*q, EZP(1,3)+4*q, EZP(2,3)+4*q); \
    float4 cq = ldf4(&cb1[chB*68 + f0B + 4*q]); \
    float4 hq = gate4(zi,zf,zo,zg, bi,bf,bo,bg, cq); \
    stf4(&cb1[chB*68 + f0B + 4*q], cq); \
    stf4(&hbuf[(17+chB)*RS + 4 + f0B + 4*q], hq); \
    stf4(seqp + 4*q, hq); }
                EQ(0, I0, F0, O0, G0)
                EQ(1, I1, F1, O1, G1)
                EQ(2, I2, F2, O2, G2)
                EQ(3, I3, F3, O3, G3)
#undef EQ
#undef EZP
            }
            __syncthreads();                                   // D
        }
    }

    // final states
    for (int i = tid; i < 1024; i += 512) {
        int ch = i >> 6, f = i & 63;
        h1f[b * 1024 + i] = hbuf[(1 + ch) * RS + 4 + f];
        c1f[b * 1024 + i] = cb0[ch * 68 + f];
    }
    for (int i = tid; i < 2048; i += 512) {
        int ch = i >> 6, f = i & 63;
        h2f[b * 2048 + i] = hbuf[(17 + ch) * RS + 4 + f];
        c2f[b * 2048 + i] = cb1[ch * 68 + f];
    }
}

// ---------------------------------------------------------------------------
// xconv0: parallel x-part pre-activations for dec0. One block per (t,b).
// ---------------------------------------------------------------------------
__global__ __launch_bounds__(256, 2) void xconv0_kernel(
    const float* __restrict__ seqIn, const float* __restrict__ w,
    float* __restrict__ zx, int t0)
{
    __shared__ float wl[96 * 128];
    __shared__ float xt[32 * RS];

    const int tid = threadIdx.x;
    const int tl = blockIdx.x / B_;
    const int b  = blockIdx.x - tl * B_;
    const int t  = t0 + tl;

    for (int idx = tid; idx < 96 * 128; idx += 256) {
        int k = idx >> 7, r = idx & 127;
        int ch = r >> 2, g = r & 3;
        int ci = k / 3, d = k - ci * 3;
        wl[idx] = w[((g * 32 + ch) * 64 + ci) * 9 + d * 3 + 1];
    }
    {
        int r = tid >> 3, j = tid & 7;
        xt[r * RS + (j < 4 ? j : 64 + j)] = 0.f;
    }
    {
        const float* s = &seqIn[((size_t)t * B_ + b) * 2048 + tid * 8];
        float4 v0 = ldf4(s);
        float4 v1 = ldf4(s + 4);
        int ci = tid >> 3, col = (tid & 7) * 8;
        stf4(&xt[ci * RS + 4 + col], v0);
        stf4(&xt[ci * RS + 4 + col + 4], v1);
    }
    __syncthreads();

    const int ch = tid >> 3, f0 = (tid & 7) * 8;
    const float4 z4 = make_float4(0.f,0.f,0.f,0.f);
    float4 i0=z4,i1=z4,f0v=z4,f1v=z4,o0=z4,o1=z4,g0=z4,g1=z4;
#pragma unroll 1
    for (int r = 0; r < 32; ++r)
        rowacc8<128>(&xt[r * RS + 4 + f0], wl + (r * 3) * 128 + ch * 4,
                     i0, i1, f0v, f1v, o0, o1, g0, g1);

    float* zp = &zx[(((size_t)tl * B_ + b) * 4) * 2048 + ch * 64 + f0];
    stf4(zp, i0);            stf4(zp + 4, i1);
    stf4(zp + 2048, f0v);    stf4(zp + 2048 + 4, f1v);
    stf4(zp + 4096, o0);     stf4(zp + 4096 + 4, o1);
    stf4(zp + 6144, g0);     stf4(zp + 6144 + 4, g1);
}

// ---------------------------------------------------------------------------
// xconv1: parallel x-part for dec1 (32 -> 16ch). One block per (t,b).
// ---------------------------------------------------------------------------
__global__ __launch_bounds__(256, 2) void xconv1_kernel(
    const float* __restrict__ seqIn, const float* __restrict__ w,
    float* __restrict__ zx, int t0)
{
    __shared__ float wl[96 * 64];
    __shared__ float xt[32 * RS];

    const int tid = threadIdx.x;
    const int tl = blockIdx.x / B_;
    const int b  = blockIdx.x - tl * B_;
    const int t  = t0 + tl;

    for (int idx = tid; idx < 96 * 64; idx += 256) {
        int k = idx >> 6, r = idx & 63;
        int ch = r >> 2, g = r & 3;
        int ci = k / 3, d = k - ci * 3;
        wl[idx] = w[((g * 16 + ch) * 48 + ci) * 9 + d * 3 + 1];
    }
    {
        int r = tid >> 3, j = tid & 7;
        xt[r * RS + (j < 4 ? j : 64 + j)] = 0.f;
    }
    {
        const float* s = &seqIn[((size_t)t * B_ + b) * 2048 + tid * 8];
        float4 v0 = ldf4(s);
        float4 v1 = ldf4(s + 4);
        int ci = tid >> 3, col = (tid & 7) * 8;
        stf4(&xt[ci * RS + 4 + col], v0);
        stf4(&xt[ci * RS + 4 + col + 4], v1);
    }
    __syncthreads();

    const int ch = tid >> 4, f0 = (tid & 15) * 4;
    const float4 z4 = make_float4(0.f,0.f,0.f,0.f);
    float4 ai=z4, af=z4, ao=z4, ag=z4;
#pragma unroll 1
    for (int r = 0; r < 32; ++r)
        rowacc4<64>(&xt[r * RS + 4 + f0], wl + (r * 3) * 64 + ch * 4, ai, af, ao, ag);

    float* zp = &zx[(((size_t)tl * B_ + b) * 4) * 1024 + ch * 64 + f0];
    stf4(zp, ai);
    stf4(zp + 1024, af);
    stf4(zp + 2048, ao);
    stf4(zp + 3072, ag);
}

// ---------------------------------------------------------------------------
// dec0k: decoder L0 recurrence (h-part only), kg-split, weights in VGPR.
// (32h)->32, FT=16. seq updated in place. 2 barriers/step. (512,1): needs
// Wv=96 + acc=64 + temps ~= 190 VGPRs; LDS 123KB -> 1 block/CU anyway.
// ---------------------------------------------------------------------------
__global__ __launch_bounds__(512, 1) void dec0k(
    const float* __restrict__ w, const float* __restrict__ bias,
    float* __restrict__ seq, const float* __restrict__ zx,
    const float* __restrict__ hin, const float* __restrict__ cin,
    float* __restrict__ hout, float* __restrict__ cout,
    int t0, int tn)
{
    __shared__ float hp[32 * RS];
    __shared__ float cb[32 * 68];
    __shared__ float zs[3 * 4 * 32 * 68];
    __shared__ float bs[128];

    const int tid = threadIdx.x, b = blockIdx.x;
    const int kg = tid >> 7, ch = tid & 31, f0 = ((tid >> 5) & 3) * 16;

    float4 Wv[8][3];
#pragma unroll
    for (int j = 0; j < 8; ++j) {
        int ci = 32 + kg * 8 + j;
#pragma unroll
        for (int d = 0; d < 3; ++d)
            Wv[j][d] = make_float4(
                w[((0 * 32 + ch) * 64 + ci) * 9 + d * 3 + 1],
                w[((1 * 32 + ch) * 64 + ci) * 9 + d * 3 + 1],
                w[((2 * 32 + ch) * 64 + ci) * 9 + d * 3 + 1],
                w[((3 * 32 + ch) * 64 + ci) * 9 + d * 3 + 1]);
    }
    if (tid < 128) bs[tid] = bias[tid];
    for (int i = tid; i < 32 * RS; i += 512) hp[i] = 0.f;
    __syncthreads();
    for (int i = tid; i < 2048; i += 512) {
        int c8 = i >> 6, f = i & 63;
        hp[c8 * RS + 4 + f] = hin[b * 2048 + i];
        cb[c8 * 68 + f] = cin[b * 2048 + i];
    }
    __syncthreads();

    const float4 z4 = make_float4(0.f, 0.f, 0.f, 0.f);

#pragma unroll 1
    for (int tl = 0; tl < tn; ++tl) {
        const int t = t0 + tl;
        float4 I0=z4,I1=z4,I2=z4,I3=z4,F0=z4,F1=z4,F2=z4,F3=z4;
        float4 O0=z4,O1=z4,O2=z4,O3=z4,G0=z4,G1=z4,G2=z4,G3=z4;
        // x-part pre-activations seed kg1 (i,f) / kg2 (o,g) accumulators
        const float* zp0 = &zx[((size_t)tl * B_ + b) * 8192 + ch * 64 + f0];
        if (kg == 1) {
            I0 = ldf4(zp0);        I1 = ldf4(zp0+4);      I2 = ldf4(zp0+8);      I3 = ldf4(zp0+12);
            F0 = ldf4(zp0+2048);   F1 = ldf4(zp0+2052);   F2 = ldf4(zp0+2056);   F3 = ldf4(zp0+2060);
        } else if (kg == 2) {
            O0 = ldf4(zp0+4096);   O1 = ldf4(zp0+4100);   O2 = ldf4(zp0+4104);   O3 = ldf4(zp0+4108);
            G0 = ldf4(zp0+6144);   G1 = ldf4(zp0+6148);   G2 = ldf4(zp0+6152);   G3 = ldf4(zp0+6156);
        }
#pragma unroll
        for (int j = 0; j < 8; ++j)
            ROW16(&hp[(kg * 8 + j) * RS + 4 + f0], Wv[j][0], Wv[j][1], Wv[j][2]);

        if (kg > 0) {
            float* zp;
            zp = &zs[(((kg-1)*4 + 0)*32 + ch)*68 + f0];
            stf4(zp, I0); stf4(zp+4, I1); stf4(zp+8, I2); stf4(zp+12, I3);
            zp = &zs[(((kg-1)*4 + 1)*32 + ch)*68 + f0];
            stf4(zp, F0); stf4(zp+4, F1); stf4(zp+8, F2); stf4(zp+12, F3);
            zp = &zs[(((kg-1)*4 + 2)*32 + ch)*68 + f0];
            stf4(zp, O0); stf4(zp+4, O1); stf4(zp+8, O2); stf4(zp+12, O3);
            zp = &zs[(((kg-1)*4 + 3)*32 + ch)*68 + f0];
            stf4(zp, G0); stf4(zp+4, G1); stf4(zp+8, G2); stf4(zp+12, G3);
        }
        __syncthreads();                                       // A
        if (kg == 0) {
            const float bi = bs[ch], bf = bs[32+ch], bo = bs[64+ch], bg = bs[96+ch];
            float* seqp = &seq[((size_t)t * B_ + b) * 2048 + ch * 64 + f0];
#define DZP(k,g) (&zs[(((k)*4+(g))*32 + ch)*68 + f0])
#define DQ(q, AI,AF,AO,AG) { \
    float4 zi = r3(AI, DZP(0,0)+4*q, DZP(1,0)+4*q, DZP(2,0)+4*q); \
    float4 zf = r3(AF, DZP(0,1)+4*q, DZP(1,1)+4*q, DZP(2,1)+4*q); \
    float4 zo = r3(AO, DZP(0,2)+4*q, DZP(1,2)+4*q, DZP(2,2)+4*q); \
    float4 zg = r3(AG, DZP(0,3)+4*q, DZP(1,3)+4*q, DZP(2,3)+4*q); \
    float4 cq = ldf4(&cb[ch*68 + f0 + 4*q]); \
    float4 hq = gate4(zi,zf,zo,zg, bi,bf,bo,bg, cq); \
    stf4(&cb[ch*68 + f0 + 4*q], cq); \
    stf4(&hp[ch*RS + 4 + f0 + 4*q], hq); \
    stf4(seqp + 4*q, hq); }
            DQ(0, I0, F0, O0, G0)
            DQ(1, I1, F1, O1, G1)
            DQ(2, I2, F2, O2, G2)
            DQ(3, I3, F3, O3, G3)
#undef DQ
#undef DZP
        }
        __syncthreads();                                       // B
    }

    for (int i = tid; i < 2048; i += 512) {
        int c8 = i >> 6, f = i & 63;
        hout[b * 2048 + i] = hp[c8 * RS + 4 + f];
        cout[b * 2048 + i] = cb[c8 * 68 + f];
    }
}

// ---------------------------------------------------------------------------
// dec1k: decoder L1 recurrence (h-part only) + final 1x1 conv.
// (16h)->16, FT=8, kg-split. 2 barriers/step. (512,1): ~110 VGPRs.
// ---------------------------------------------------------------------------
__global__ __launch_bounds__(512, 1) void dec1k(
    const float* __restrict__ w, const float* __restrict__ bias,
    const float* __restrict__ zx,
    const float* __restrict__ hin, const float* __restrict__ cin,
    float* __restrict__ hout, float* __restrict__ cout,
    const float* __restrict__ fw, const float* __restrict__ fb,
    float* __restrict__ out, int t0, int tn)
{
    __shared__ float hp[16 * RS];
    __shared__ float cb[16 * 68];
    __shared__ float zs[3 * 4 * 16 * 68];
    __shared__ float bs[64];
    __shared__ float fcw[16];
    __shared__ float fcb;

    const int tid = threadIdx.x, b = blockIdx.x;
    const int kg = tid >> 7, ch = tid & 15, f0 = ((tid >> 4) & 7) * 8;

    float4 Wv[4][3];
#pragma unroll
    for (int j = 0; j < 4; ++j) {
        int ci = 32 + kg * 4 + j;
#pragma unroll
        for (int d = 0; d < 3; ++d)
            Wv[j][d] = make_float4(
                w[((0 * 16 + ch) * 48 + ci) * 9 + d * 3 + 1],
                w[((1 * 16 + ch) * 48 + ci) * 9 + d * 3 + 1],
                w[((2 * 16 + ch) * 48 + ci) * 9 + d * 3 + 1],
                w[((3 * 16 + ch) * 48 + ci) * 9 + d * 3 + 1]);
    }
    if (tid < 64) bs[tid] = bias[tid];
    if (tid < 16) fcw[tid] = fw[tid];
    if (tid == 16) fcb = fb[0];
    for (int i = tid; i < 16 * RS; i += 512) hp[i] = 0.f;
    __syncthreads();
    for (int i = tid; i < 1024; i += 512) {
        int c8 = i >> 6, f = i & 63;
        hp[c8 * RS + 4 + f] = hin[b * 1024 + i];
        cb[c8 * 68 + f] = cin[b * 1024 + i];
    }
    __syncthreads();

    const float4 z4 = make_float4(0.f, 0.f, 0.f, 0.f);

#pragma unroll 1
    for (int tl = 0; tl < tn; ++tl) {
        const int t = t0 + tl;
        float4 I0=z4,I1=z4,F0=z4,F1=z4,O0=z4,O1=z4,G0=z4,G1=z4;
        const float* zp0 = &zx[((size_t)tl * B_ + b) * 4096 + ch * 64 + f0];
        if (kg == 1) {
            I0 = ldf4(zp0);        I1 = ldf4(zp0+4);
            F0 = ldf4(zp0+1024);   F1 = ldf4(zp0+1028);
        } else if (kg == 2) {
            O0 = ldf4(zp0+2048);   O1 = ldf4(zp0+2052);
            G0 = ldf4(zp0+3072);   G1 = ldf4(zp0+3076);
        }
#pragma unroll
        for (int j = 0; j < 4; ++j)
            ROW8(&hp[(kg * 4 + j) * RS + 4 + f0], Wv[j][0], Wv[j][1], Wv[j][2]);

        if (kg > 0) {
            float* zp;
            zp = &zs[(((kg-1)*4 + 0)*16 + ch)*68 + f0]; stf4(zp, I0); stf4(zp+4, I1);
            zp = &zs[(((kg-1)*4 + 1)*16 + ch)*68 + f0]; stf4(zp, F0); stf4(zp+4, F1);
            zp = &zs[(((kg-1)*4 + 2)*16 + ch)*68 + f0]; stf4(zp, O0); stf4(zp+4, O1);
            zp = &zs[(((kg-1)*4 + 3)*16 + ch)*68 + f0]; stf4(zp, G0); stf4(zp+4, G1);
        }
        __syncthreads();                                       // A
        if (kg == 0) {
            const float bi = bs[ch], bf = bs[16+ch], bo = bs[32+ch], bg = bs[48+ch];
#define TZP(k,g) (&zs[(((k)*4+(g))*16 + ch)*68 + f0])
#define TQ(q, AI,AF,AO,AG) { \
    float4 zi = r3(AI, TZP(0,0)+4*q, TZP(1,0)+4*q, TZP(2,0)+4*q); \
    float4 zf = r3(AF, TZP(0,1)+4*q, TZP(1,1)+4*q, TZP(2,1)+4*q); \
    float4 zo = r3(AO, TZP(0,2)+4*q, TZP(1,2)+4*q, TZP(2,2)+4*q); \
    float4 zg = r3(AG, TZP(0,3)+4*q, TZP(1,3)+4*q, TZP(2,3)+4*q); \
    float4 cq = ldf4(&cb[ch*68 + f0 + 4*q]); \
    float4 hq = gate4(zi,zf,zo,zg, bi,bf,bo,bg, cq); \
    stf4(&cb[ch*68 + f0 + 4*q], cq); \
    stf4(&hp[ch*RS + 4 + f0 + 4*q], hq); }
            TQ(0, I0, F0, O0, G0)
            TQ(1, I1, F1, O1, G1)
#undef TQ
#undef TZP
        }
        __syncthreads();                                       // B
        if (tid < 64) {
            float a = fcb;
#pragma unroll
            for (int k2 = 0; k2 < 16; ++k2)
                a = fmaf(fcw[k2], hp[k2 * RS + 4 + tid], a);
            out[(b * T_ + t) * 64 + tid] = a;
        }
    }

    for (int i = tid; i < 1024; i += 512) {
        int c8 = i >> 6, f = i & 63;
        hout[b * 1024 + i] = hp[c8 * RS + 4 + f];
        cout[b * 1024 + i] = cb[c8 * 68 + f];
    }
}

// ---------------------------------------------------------------------------
// Fallback (ws too small for zx): fused x+h decoders, round-4 structure.
// ---------------------------------------------------------------------------
__global__ __launch_bounds__(512, 1) void dec0_fb(
    const float* __restrict__ w, const float* __restrict__ bias,
    float* __restrict__ seq,
    const float* __restrict__ hin, const float* __restrict__ cin)
{
    __shared__ float wl[192 * 128];
    __shared__ float bs[128];
    __shared__ float xin[32 * RS];
    __shared__ float hp[32 * RS];

    const int tid = threadIdx.x;
    const int b = blockIdx.x;

    for (int idx = tid; idx < 192 * 128; idx += 512) {
        int k = idx >> 7, r = idx & 127;
        int ch = r >> 2, g = r & 3;
        int ci = k / 3, d = k - ci * 3;
        wl[idx] = w[((g * 32 + ch) * 64 + ci) * 9 + d * 3 + 1];
    }
    if (tid < 128) bs[tid] = bias[tid];
    for (int i = tid; i < 32 * RS; i += 512) { xin[i] = 0.f; hp[i] = 0.f; }
    __syncthreads();
    {
        const float* hs = &hin[b * 2048 + tid * 4];
        float4 hv = ldf4(hs);
        int ci = tid >> 4, col = (tid & 15) * 4;
        stf4(&hp[ci * RS + 4 + col], hv);
    }
    const int ch = tid >> 4, f0 = (tid & 15) * 4;
    float4 cc = ldf4(&cin[b * 2048 + ch * 64 + f0]);
    const float bi = bs[ch], bf = bs[32 + ch], bo = bs[64 + ch], bg = bs[96 + ch];
    const float4 z4 = make_float4(0.f,0.f,0.f,0.f);

    float4 nx = ldf4(&seq[(size_t)b * 2048 + tid * 4]);

#pragma unroll 1
    for (int t = 0; t < T_; ++t) {
        {
            int ci = tid >> 4, col = (tid & 15) * 4;
            stf4(&xin[ci * RS + 4 + col], nx);
        }
        __syncthreads();
        if (t + 1 < T_)
            nx = ldf4(&seq[((size_t)(t + 1) * B_ + b) * 2048 + tid * 4]);
        float4 ai = z4, af = z4, ao = z4, ag = z4;
#pragma unroll 1
        for (int r = 0; r < 32; ++r)
            rowacc4<128>(&xin[r * RS + 4 + f0], wl + (r * 3) * 128 + ch * 4, ai, af, ao, ag);
#pragma unroll 1
        for (int r = 0; r < 32; ++r)
            rowacc4<128>(&hp[r * RS + 4 + f0], wl + ((32 + r) * 3) * 128 + ch * 4, ai, af, ao, ag);
        float4 hn = gate4(ai, af, ao, ag, bi, bf, bo, bg, cc);
        __syncthreads();
        stf4(&hp[ch * RS + 4 + f0], hn);
        stf4(&seq[((size_t)t * B_ + b) * 2048 + ch * 64 + f0], hn);
    }
}

__global__ __launch_bounds__(512, 1) void dec1_fb(
    const float* __restrict__ w, const float* __restrict__ bias,
    const float* __restrict__ seq,
    const float* __restrict__ hin, const float* __restrict__ cin,
    const float* __restrict__ fw, const float* __restrict__ fb,
    float* __restrict__ out)
{
    __shared__ float wl[144 * 64];
    __shared__ float bs[64];
    __shared__ float xin[32 * RS];
    __shared__ float hp[16 * RS];
    __shared__ float fcw[16];
    __shared__ float fcb;

    const int tid = threadIdx.x;
    const int b = blockIdx.x;

    for (int idx = tid; idx < 144 * 64; idx += 512) {
        int k = idx >> 6, r = idx & 63;
        int ch = r >> 2, g = r & 3;
        int ci = k / 3, d = k - ci * 3;
        wl[idx] = w[((g * 16 + ch) * 48 + ci) * 9 + d * 3 + 1];
    }
    if (tid < 64) bs[tid] = bias[tid];
    if (tid < 16) fcw[tid] = fw[tid];
    if (tid == 16) fcb = fb[0];
    for (int i = tid; i < 32 * RS; i += 512) xin[i] = 0.f;
    for (int i = tid; i < 16 * RS; i += 512) hp[i] = 0.f;
    __syncthreads();
    {
        const float* hs = &hin[b * 1024 + tid * 2];
        float2 hv = *reinterpret_cast<const float2*>(hs);
        int ci = tid >> 5, col = (tid & 31) * 2;
        *reinterpret_cast<float2*>(&hp[ci * RS + 4 + col]) = hv;
    }
    const int ch = tid >> 5, f0 = (tid & 31) * 2;
    float2 cc = *reinterpret_cast<const float2*>(&cin[b * 1024 + ch * 64 + f0]);
    const float bi = bs[ch], bf = bs[16 + ch], bo = bs[32 + ch], bg = bs[48 + ch];
    const float2 z2 = make_float2(0.f,0.f);
    float4 nx = ldf4(&seq[(size_t)b * 2048 + tid * 4]);
    __syncthreads();

#pragma unroll 1
    for (int t = 0; t < T_; ++t) {
        {
            int ci = tid >> 4, col = (tid & 15) * 4;
            stf4(&xin[ci * RS + 4 + col], nx);
        }
        __syncthreads();
        if (t + 1 < T_)
            nx = ldf4(&seq[((size_t)(t + 1) * B_ + b) * 2048 + tid * 4]);

        float2 ai = z2, af = z2, ao = z2, ag = z2;
#pragma unroll 1
        for (int r = 0; r < 32; ++r)
            rowacc2<64>(&xin[r * RS + 4 + f0], wl + (r * 3) * 64 + ch * 4, ai, af, ao, ag);
#pragma unroll 1
        for (int r = 0; r < 16; ++r)
            rowacc2<64>(&hp[r * RS + 4 + f0], wl + ((32 + r) * 3) * 64 + ch * 4, ai, af, ao, ag);

        float2 hh;
        hh.x = gate1(ai.x + bi, af.x + bf, ao.x + bo, ag.x + bg, cc.x);
        hh.y = gate1(ai.y + bi, af.y + bf, ao.y + bo, ag.y + bg, cc.y);
        __syncthreads();
        *reinterpret_cast<float2*>(&hp[ch * RS + 4 + f0]) = hh;
        __syncthreads();

        if (tid < 64) {
            float a = fcb;
#pragma unroll
            for (int k2 = 0; k2 < 16; ++k2)
                a = fmaf(fcw[k2], hp[k2 * RS + 4 + tid], a);
            out[(b * T_ + t) * 64 + tid] = a;
        }
    }
}

// ---------------------------------------------------------------------------
extern "C" void kernel_launch(void* const* d_in, const int* in_sizes, int n_in,
                              void* d_out, int out_size, void* d_ws, size_t ws_size,
                              hipStream_t stream)
{
    (void)in_sizes; (void)n_in; (void)out_size;
    const float* x   = (const float*)d_in[0];
    const float* ew0 = (const float*)d_in[1];
    const float* eb0 = (const float*)d_in[2];
    const float* ew1 = (const float*)d_in[3];
    const float* eb1 = (const float*)d_in[4];
    const float* dw0 = (const float*)d_in[5];
    const float* db0 = (const float*)d_in[6];
    const float* dw1 = (const float*)d_in[7];
    const float* db1 = (const float*)d_in[8];
    const float* fw  = (const float*)d_in[9];
    const float* fb  = (const float*)d_in[10];
    float* out = (float*)d_out;

    float* ws  = (float*)d_ws;
    size_t off = 0;
    float* seq = ws + off; off += (size_t)T_ * B_ * 2048;
    float* h1f = ws + off; off += (size_t)B_ * 1024;
    float* c1f = ws + off; off += (size_t)B_ * 1024;
    float* h2f = ws + off; off += (size_t)B_ * 2048;
    float* c2f = ws + off; off += (size_t)B_ * 2048;
    float* hd0 = ws + off; off += (size_t)B_ * 2048;
    float* cd0 = ws + off; off += (size_t)B_ * 2048;
    float* hd1 = ws + off; off += (size_t)B_ * 1024;
    float* cd1 = ws + off; off += (size_t)B_ * 1024;
    float* zx  = ws + off;

    size_t availf = (ws_size / 4 > off) ? (ws_size / 4 - off) : 0;
    int TC = 0;
    if      (availf >= (size_t)100 * B_ * 8192) TC = 100;
    else if (availf >= (size_t)50  * B_ * 8192) TC = 50;
    else if (availf >= (size_t)25  * B_ * 8192) TC = 25;
    else if (availf >= (size_t)10  * B_ * 8192) TC = 10;

    enc_kernel<<<B_, 512, 0, stream>>>(x, ew0, eb0, ew1, eb1, seq, h1f, c1f, h2f, c2f);

    if (TC > 0) {
        for (int t0 = 0; t0 < T_; t0 += TC) {
            xconv0_kernel<<<TC * B_, 256, 0, stream>>>(seq, dw0, zx, t0);
            dec0k<<<B_, 512, 0, stream>>>(
                dw0, db0, seq, zx,
                t0 == 0 ? h2f : hd0, t0 == 0 ? c2f : cd0, hd0, cd0, t0, TC);
        }
        for (int t0 = 0; t0 < T_; t0 += TC) {
            xconv1_kernel<<<TC * B_, 256, 0, stream>>>(seq, dw1, zx, t0);
            dec1k<<<B_, 512, 0, stream>>>(
                dw1, db1, zx,
                t0 == 0 ? h1f : hd1, t0 == 0 ? c1f : cd1, hd1, cd1,
                fw, fb, out, t0, TC);
        }
    } else {
        dec0_fb<<<B_, 512, 0, stream>>>(dw0, db0, seq, h2f, c2f);
        dec1_fb<<<B_, 512, 0, stream>>>(dw1, db1, seq, h1f, c1f, fw, fb, out);
    }
}

// Round 7
// 2504.174 us; speedup vs baseline: 5.7197x; 5.7095x over previous
//
#include <hip/hip_runtime.h>
#include <math.h>

#define B_ 128
#define T_ 100
#define RS 72      // padded row stride (words); data cols [4..67]; [0..3],[68..71] zero

// ---------------------------------------------------------------------------
// Fast transcendentals (~1e-6 rel err; threshold 1.27e-4)
// ---------------------------------------------------------------------------
__device__ __forceinline__ float frcp_(float x){ return __builtin_amdgcn_rcpf(x); }
__device__ __forceinline__ float fsig_(float x){ return frcp_(1.f + __expf(-x)); }
__device__ __forceinline__ float ftanh_(float x){ float e = __expf(2.f*x); return 1.f - 2.f*frcp_(e+1.f); }
__device__ __forceinline__ float gate1(float zi, float zf, float zo, float zg, float& c){
    float cc = fsig_(zf)*c + fsig_(zi)*ftanh_(zg);
    c = cc;
    return fsig_(zo)*ftanh_(cc);
}
__device__ __forceinline__ float4 ldf4(const float* p){ return *reinterpret_cast<const float4*>(p); }
__device__ __forceinline__ void stf4(float* p, float4 v){ *reinterpret_cast<float4*>(p) = v; }
__device__ __forceinline__ float4 add4(float4 a, float4 b){
    return make_float4(a.x+b.x, a.y+b.y, a.z+b.z, a.w+b.w);
}
__device__ __forceinline__ float4 gate4(float4 zi, float4 zf, float4 zo, float4 zg,
                                        float bi, float bf, float bo, float bg, float4& c){
    float4 h;
    h.x = gate1(zi.x+bi, zf.x+bf, zo.x+bo, zg.x+bg, c.x);
    h.y = gate1(zi.y+bi, zf.y+bf, zo.y+bo, zg.y+bg, c.y);
    h.z = gate1(zi.z+bi, zf.z+bf, zo.z+bo, zg.z+bg, c.z);
    h.w = gate1(zi.w+bi, zf.w+bf, zo.w+bo, zg.w+bg, c.w);
    return h;
}

__device__ __forceinline__ void fma4v(float w, float u0,float u1,float u2,float u3, float4& a){
    a.x = fmaf(w,u0,a.x); a.y = fmaf(w,u1,a.y);
    a.z = fmaf(w,u2,a.z); a.w = fmaf(w,u3,a.w);
}
__device__ __forceinline__ void fma2v(float w, float u0,float u1, float2& a){
    a.x = fmaf(w,u0,a.x); a.y = fmaf(w,u1,a.y);
}

// ---------------------------------------------------------------------------
// Row accumulators, weights from LDS. rowp = &buf[row*RS + 4 + f0] (16B align).
// wk = wl + (krow*3)*ROWS + ch*4 ; tap d weight float4 at wk + d*ROWS.
// ---------------------------------------------------------------------------
template<int ROWS>
__device__ __forceinline__ void rowacc4(const float* __restrict__ rowp,
                                        const float* __restrict__ wk,
                                        float4& ai, float4& af, float4& ao, float4& ag)
{
    float  m = rowp[-1];
    float4 a = ldf4(rowp);
    float  p = rowp[4];
    float4 wa = ldf4(wk);
    float4 wb = ldf4(wk + ROWS);
    float4 wc = ldf4(wk + 2*ROWS);
    fma4v(wa.x, m,a.x,a.y,a.z, ai);  fma4v(wa.y, m,a.x,a.y,a.z, af);
    fma4v(wa.z, m,a.x,a.y,a.z, ao);  fma4v(wa.w, m,a.x,a.y,a.z, ag);
    fma4v(wb.x, a.x,a.y,a.z,a.w, ai); fma4v(wb.y, a.x,a.y,a.z,a.w, af);
    fma4v(wb.z, a.x,a.y,a.z,a.w, ao); fma4v(wb.w, a.x,a.y,a.z,a.w, ag);
    fma4v(wc.x, a.y,a.z,a.w,p, ai);  fma4v(wc.y, a.y,a.z,a.w,p, af);
    fma4v(wc.z, a.y,a.z,a.w,p, ao);  fma4v(wc.w, a.y,a.z,a.w,p, ag);
}
template<int ROWS>
__device__ __forceinline__ void rowacc2(const float* __restrict__ rowp,
                                        const float* __restrict__ wk,
                                        float2& ai, float2& af, float2& ao, float2& ag)
{
    float  m = rowp[-1];
    float2 a = *reinterpret_cast<const float2*>(rowp);
    float  p = rowp[2];
    float4 wa = ldf4(wk);
    float4 wb = ldf4(wk + ROWS);
    float4 wc = ldf4(wk + 2*ROWS);
    fma2v(wa.x, m,a.x, ai); fma2v(wa.y, m,a.x, af);
    fma2v(wa.z, m,a.x, ao); fma2v(wa.w, m,a.x, ag);
    fma2v(wb.x, a.x,a.y, ai); fma2v(wb.y, a.x,a.y, af);
    fma2v(wb.z, a.x,a.y, ao); fma2v(wb.w, a.x,a.y, ag);
    fma2v(wc.x, a.y,p, ai); fma2v(wc.y, a.y,p, af);
    fma2v(wc.z, a.y,p, ao); fma2v(wc.w, a.y,p, ag);
}
template<int ROWS>
__device__ __forceinline__ void rowacc8(const float* __restrict__ rowp,
                                        const float* __restrict__ wk,
                                        float4& i0, float4& i1, float4& f0v, float4& f1v,
                                        float4& o0, float4& o1, float4& g0, float4& g1)
{
    float  m = rowp[-1];
    float4 a = ldf4(rowp);
    float4 b = ldf4(rowp + 4);
    float  p = rowp[8];
    float4 wa = ldf4(wk);
    float4 wb = ldf4(wk + ROWS);
    float4 wc = ldf4(wk + 2*ROWS);
    fma4v(wa.x, m,a.x,a.y,a.z, i0);   fma4v(wa.x, a.w,b.x,b.y,b.z, i1);
    fma4v(wa.y, m,a.x,a.y,a.z, f0v);  fma4v(wa.y, a.w,b.x,b.y,b.z, f1v);
    fma4v(wa.z, m,a.x,a.y,a.z, o0);   fma4v(wa.z, a.w,b.x,b.y,b.z, o1);
    fma4v(wa.w, m,a.x,a.y,a.z, g0);   fma4v(wa.w, a.w,b.x,b.y,b.z, g1);
    fma4v(wb.x, a.x,a.y,a.z,a.w, i0); fma4v(wb.x, b.x,b.y,b.z,b.w, i1);
    fma4v(wb.y, a.x,a.y,a.z,a.w, f0v);fma4v(wb.y, b.x,b.y,b.z,b.w, f1v);
    fma4v(wb.z, a.x,a.y,a.z,a.w, o0); fma4v(wb.z, b.x,b.y,b.z,b.w, o1);
    fma4v(wb.w, a.x,a.y,a.z,a.w, g0); fma4v(wb.w, b.x,b.y,b.z,b.w, g1);
    fma4v(wc.x, a.y,a.z,a.w,b.x, i0); fma4v(wc.x, b.y,b.z,b.w,p, i1);
    fma4v(wc.y, a.y,a.z,a.w,b.x, f0v);fma4v(wc.y, b.y,b.z,b.w,p, f1v);
    fma4v(wc.z, a.y,a.z,a.w,b.x, o0); fma4v(wc.z, b.y,b.z,b.w,p, o1);
    fma4v(wc.w, a.y,a.z,a.w,b.x, g0); fma4v(wc.w, b.y,b.z,b.w,p, g1);
}

// ---------------------------------------------------------------------------
// Encoder. 512 thr, kg=2 split, weights in LDS, 2 barriers/step.
// P1: all threads accumulate L1(t) (24 rows each) + L0(t+1) (8-9 rows each,
//     kg-split); kg1 writes partials to zs. P2: kg0 combines + gates + writes.
// hbuf rows: 0,1 = x double-buffer; 2..17 = h0; 18..49 = h1.
// VGPR budget ~100 (fits the 128 cap the compiler imposes on 512-thr blocks).
// ---------------------------------------------------------------------------
__global__ __launch_bounds__(512, 1) void enc_kernel(
    const float* __restrict__ x,
    const float* __restrict__ w0, const float* __restrict__ b0,
    const float* __restrict__ w1, const float* __restrict__ b1,
    float* __restrict__ seq,
    float* __restrict__ h1f, float* __restrict__ c1f,
    float* __restrict__ h2f, float* __restrict__ c2f)
{
    __shared__ float wl0[51 * 64];     // k=(ci*3+d), ci<17, col=ch*4+g (CH=16)
    __shared__ float wl1[144 * 128];   // ci<48 (0..15 = h0, 16..47 = h1)
    __shared__ float bs0[64];
    __shared__ float bs1[128];
    __shared__ float hbuf[50 * RS];
    __shared__ float zsA[4 * 16 * 64];
    __shared__ float zsB[4 * 32 * 64];

    const int tid = threadIdx.x;
    const int b = blockIdx.x;
    const int kg = tid >> 8;            // 0/1 (waves 0-3 / 4-7)
    const int r  = tid & 255;
    const int chA = r >> 4, f0A = (r & 15) * 4;   // L0: 16ch x 16fg, FT=4
    const int chB = r >> 3, f0B = (r & 7) * 8;    // L1: 32ch x 8fg, FT=8

    for (int idx = tid; idx < 51 * 64; idx += 512) {
        int k = idx >> 6, rr = idx & 63;
        int ch = rr >> 2, g = rr & 3;
        int ci = k / 3, d = k - ci * 3;
        wl0[idx] = w0[((g * 16 + ch) * 17 + ci) * 9 + d * 3 + 1];
    }
    for (int idx = tid; idx < 144 * 128; idx += 512) {
        int k = idx >> 7, rr = idx & 127;
        int ch = rr >> 2, g = rr & 3;
        int ci = k / 3, d = k - ci * 3;
        wl1[idx] = w1[((g * 32 + ch) * 48 + ci) * 9 + d * 3 + 1];
    }
    if (tid < 64) bs0[tid] = b0[tid];
    if (tid < 128) bs1[tid] = b1[tid];
    for (int i = tid; i < 50 * RS; i += 512) hbuf[i] = 0.f;
    __syncthreads();

    const int xl = tid - 256;      // wave 4 stages x
    if (xl >= 0 && xl < 64) {
        hbuf[0 * RS + 4 + xl] = x[(b * T_ + 0) * 64 + xl];
        hbuf[1 * RS + 4 + xl] = x[(b * T_ + 1) * 64 + xl];
    }
    const float biA = bs0[chA], bfA = bs0[16+chA], boA = bs0[32+chA], bgA = bs0[48+chA];
    const float biB = bs1[chB], bfB = bs1[32+chB], boB = bs1[64+chB], bgB = bs1[96+chB];
    __syncthreads();

    const float4 z4 = make_float4(0.f, 0.f, 0.f, 0.f);
    float4 c0q = z4;                  // L0 cell (kg0, 4 cols)
    float4 c1a = z4, c1b = z4;        // L1 cell (kg0, 8 cols)

    // ---- prologue: L0(0) (h0 rows are zero; x in buf row 0) ----
    {
        float4 ai = z4, af = z4, ao = z4, ag = z4;
        if (kg == 0) {
            rowacc4<64>(&hbuf[0 * RS + 4 + f0A], &wl0[chA * 4], ai, af, ao, ag);
        } else {
            stf4(&zsA[(0*16+chA)*64 + f0A], ai);
            stf4(&zsA[(1*16+chA)*64 + f0A], af);
            stf4(&zsA[(2*16+chA)*64 + f0A], ao);
            stf4(&zsA[(3*16+chA)*64 + f0A], ag);
        }
        __syncthreads();
        if (kg == 0) {
            float4 zi = add4(ai, ldf4(&zsA[(0*16+chA)*64 + f0A]));
            float4 zf = add4(af, ldf4(&zsA[(1*16+chA)*64 + f0A]));
            float4 zo = add4(ao, ldf4(&zsA[(2*16+chA)*64 + f0A]));
            float4 zg = add4(ag, ldf4(&zsA[(3*16+chA)*64 + f0A]));
            float4 hq = gate4(zi, zf, zo, zg, biA, bfA, boA, bgA, c0q);
            stf4(&hbuf[(2 + chA) * RS + 4 + f0A], hq);
        }
        __syncthreads();
    }

#pragma unroll 1
    for (int t = 0; t < T_; ++t) {
        const bool doL0 = (t + 1 < T_);
        // ================= P1: accumulate =================
        float4 I0=z4,I1=z4,F0=z4,F1=z4,O0=z4,O1=z4,G0=z4,G1=z4;   // L1(t)
#pragma unroll 1
        for (int j = 0; j < 24; ++j) {
            const int ci = kg * 24 + j;
            rowacc8<128>(&hbuf[(2 + ci) * RS + 4 + f0B], &wl1[(ci * 3) * 128 + chB * 4],
                         I0, I1, F0, F1, O0, O1, G0, G1);
        }
        float4 ai = z4, af = z4, ao = z4, ag = z4;                 // L0(t+1)
        if (doL0) {
            if (kg == 0) {
                rowacc4<64>(&hbuf[((t + 1) & 1) * RS + 4 + f0A], &wl0[chA * 4],
                            ai, af, ao, ag);
#pragma unroll 1
                for (int j = 0; j < 8; ++j)
                    rowacc4<64>(&hbuf[(2 + j) * RS + 4 + f0A],
                                &wl0[((1 + j) * 3) * 64 + chA * 4], ai, af, ao, ag);
            } else {
#pragma unroll 1
                for (int j = 8; j < 16; ++j)
                    rowacc4<64>(&hbuf[(2 + j) * RS + 4 + f0A],
                                &wl0[((1 + j) * 3) * 64 + chA * 4], ai, af, ao, ag);
            }
        }
        if (kg == 1) {
            stf4(&zsB[(0*32+chB)*64 + f0B], I0); stf4(&zsB[(0*32+chB)*64 + f0B + 4], I1);
            stf4(&zsB[(1*32+chB)*64 + f0B], F0); stf4(&zsB[(1*32+chB)*64 + f0B + 4], F1);
            stf4(&zsB[(2*32+chB)*64 + f0B], O0); stf4(&zsB[(2*32+chB)*64 + f0B + 4], O1);
            stf4(&zsB[(3*32+chB)*64 + f0B], G0); stf4(&zsB[(3*32+chB)*64 + f0B + 4], G1);
            if (doL0) {
                stf4(&zsA[(0*16+chA)*64 + f0A], ai);
                stf4(&zsA[(1*16+chA)*64 + f0A], af);
                stf4(&zsA[(2*16+chA)*64 + f0A], ao);
                stf4(&zsA[(3*16+chA)*64 + f0A], ag);
            }
            if (xl >= 0 && xl < 64 && t + 2 < T_)
                hbuf[(t & 1) * RS + 4 + xl] = x[(b * T_ + t + 2) * 64 + xl];
        }
        __syncthreads();                                           // Y
        // ================= P2: kg0 combine + gates =================
        if (kg == 0) {
            float4 zi0 = add4(I0, ldf4(&zsB[(0*32+chB)*64 + f0B]));
            float4 zi1 = add4(I1, ldf4(&zsB[(0*32+chB)*64 + f0B + 4]));
            float4 zf0 = add4(F0, ldf4(&zsB[(1*32+chB)*64 + f0B]));
            float4 zf1 = add4(F1, ldf4(&zsB[(1*32+chB)*64 + f0B + 4]));
            float4 zo0 = add4(O0, ldf4(&zsB[(2*32+chB)*64 + f0B]));
            float4 zo1 = add4(O1, ldf4(&zsB[(2*32+chB)*64 + f0B + 4]));
            float4 zg0 = add4(G0, ldf4(&zsB[(3*32+chB)*64 + f0B]));
            float4 zg1 = add4(G1, ldf4(&zsB[(3*32+chB)*64 + f0B + 4]));
            float4 h0q = gate4(zi0, zf0, zo0, zg0, biB, bfB, boB, bgB, c1a);
            float4 h1q = gate4(zi1, zf1, zo1, zg1, biB, bfB, boB, bgB, c1b);
            stf4(&hbuf[(18 + chB) * RS + 4 + f0B], h0q);
            stf4(&hbuf[(18 + chB) * RS + 4 + f0B + 4], h1q);
            float* sp = &seq[((size_t)t * B_ + b) * 2048 + chB * 64 + f0B];
            stf4(sp, h0q); stf4(sp + 4, h1q);
            if (doL0) {
                float4 zi = add4(ai, ldf4(&zsA[(0*16+chA)*64 + f0A]));
                float4 zf = add4(af, ldf4(&zsA[(1*16+chA)*64 + f0A]));
                float4 zo = add4(ao, ldf4(&zsA[(2*16+chA)*64 + f0A]));
                float4 zg = add4(ag, ldf4(&zsA[(3*16+chA)*64 + f0A]));
                float4 hq = gate4(zi, zf, zo, zg, biA, bfA, boA, bgA, c0q);
                stf4(&hbuf[(2 + chA) * RS + 4 + f0A], hq);
            }
        }
        __syncthreads();                                           // Z
    }

    // final states (kg0 threads own every tile exactly once)
    if (kg == 0) {
        stf4(&h1f[(b * 16 + chA) * 64 + f0A], ldf4(&hbuf[(2 + chA) * RS + 4 + f0A]));
        stf4(&c1f[(b * 16 + chA) * 64 + f0A], c0q);
        float* hp2 = &h2f[b * 2048 + chB * 64 + f0B];
        stf4(hp2,     ldf4(&hbuf[(18 + chB) * RS + 4 + f0B]));
        stf4(hp2 + 4, ldf4(&hbuf[(18 + chB) * RS + 4 + f0B + 4]));
        float* cp2 = &c2f[b * 2048 + chB * 64 + f0B];
        stf4(cp2, c1a); stf4(cp2 + 4, c1b);
    }
}

// ---------------------------------------------------------------------------
// xconv0: parallel x-part pre-activations for dec0. One block per (t,b).
// ---------------------------------------------------------------------------
__global__ __launch_bounds__(256, 2) void xconv0_kernel(
    const float* __restrict__ seqIn, const float* __restrict__ w,
    float* __restrict__ zx, int t0)
{
    __shared__ float wl[96 * 128];
    __shared__ float xt[32 * RS];

    const int tid = threadIdx.x;
    const int tl = blockIdx.x / B_;
    const int b  = blockIdx.x - tl * B_;
    const int t  = t0 + tl;

    for (int idx = tid; idx < 96 * 128; idx += 256) {
        int k = idx >> 7, rr = idx & 127;
        int ch = rr >> 2, g = rr & 3;
        int ci = k / 3, d = k - ci * 3;
        wl[idx] = w[((g * 32 + ch) * 64 + ci) * 9 + d * 3 + 1];
    }
    {
        int rr = tid >> 3, j = tid & 7;
        xt[rr * RS + (j < 4 ? j : 64 + j)] = 0.f;
    }
    {
        const float* s = &seqIn[((size_t)t * B_ + b) * 2048 + tid * 8];
        float4 v0 = ldf4(s);
        float4 v1 = ldf4(s + 4);
        int ci = tid >> 3, col = (tid & 7) * 8;
        stf4(&xt[ci * RS + 4 + col], v0);
        stf4(&xt[ci * RS + 4 + col + 4], v1);
    }
    __syncthreads();

    const int ch = tid >> 3, f0 = (tid & 7) * 8;
    const float4 z4 = make_float4(0.f,0.f,0.f,0.f);
    float4 i0=z4,i1=z4,f0v=z4,f1v=z4,o0=z4,o1=z4,g0=z4,g1=z4;
#pragma unroll 1
    for (int rr = 0; rr < 32; ++rr)
        rowacc8<128>(&xt[rr * RS + 4 + f0], wl + (rr * 3) * 128 + ch * 4,
                     i0, i1, f0v, f1v, o0, o1, g0, g1);

    float* zp = &zx[(((size_t)tl * B_ + b) * 4) * 2048 + ch * 64 + f0];
    stf4(zp, i0);            stf4(zp + 4, i1);
    stf4(zp + 2048, f0v);    stf4(zp + 2048 + 4, f1v);
    stf4(zp + 4096, o0);     stf4(zp + 4096 + 4, o1);
    stf4(zp + 6144, g0);     stf4(zp + 6144 + 4, g1);
}

// ---------------------------------------------------------------------------
// xconv1: parallel x-part for dec1 (32 -> 16ch). One block per (t,b).
// ---------------------------------------------------------------------------
__global__ __launch_bounds__(256, 2) void xconv1_kernel(
    const float* __restrict__ seqIn, const float* __restrict__ w,
    float* __restrict__ zx, int t0)
{
    __shared__ float wl[96 * 64];
    __shared__ float xt[32 * RS];

    const int tid = threadIdx.x;
    const int tl = blockIdx.x / B_;
    const int b  = blockIdx.x - tl * B_;
    const int t  = t0 + tl;

    for (int idx = tid; idx < 96 * 64; idx += 256) {
        int k = idx >> 6, rr = idx & 63;
        int ch = rr >> 2, g = rr & 3;
        int ci = k / 3, d = k - ci * 3;
        wl[idx] = w[((g * 16 + ch) * 48 + ci) * 9 + d * 3 + 1];
    }
    {
        int rr = tid >> 3, j = tid & 7;
        xt[rr * RS + (j < 4 ? j : 64 + j)] = 0.f;
    }
    {
        const float* s = &seqIn[((size_t)t * B_ + b) * 2048 + tid * 8];
        float4 v0 = ldf4(s);
        float4 v1 = ldf4(s + 4);
        int ci = tid >> 3, col = (tid & 7) * 8;
        stf4(&xt[ci * RS + 4 + col], v0);
        stf4(&xt[ci * RS + 4 + col + 4], v1);
    }
    __syncthreads();

    const int ch = tid >> 4, f0 = (tid & 15) * 4;
    const float4 z4 = make_float4(0.f,0.f,0.f,0.f);
    float4 ai=z4, af=z4, ao=z4, ag=z4;
#pragma unroll 1
    for (int rr = 0; rr < 32; ++rr)
        rowacc4<64>(&xt[rr * RS + 4 + f0], wl + (rr * 3) * 64 + ch * 4, ai, af, ao, ag);

    float* zp = &zx[(((size_t)tl * B_ + b) * 4) * 1024 + ch * 64 + f0];
    stf4(zp, ai);
    stf4(zp + 1024, af);
    stf4(zp + 2048, ao);
    stf4(zp + 3072, ag);
}

// ---------------------------------------------------------------------------
// dec0k: decoder L0 h-recurrence. 512 thr, kg=2, weights in LDS, FT=8.
// x-part comes from zx (prefetched to regs in P1). 2 barriers/step.
// ---------------------------------------------------------------------------
__global__ __launch_bounds__(512, 1) void dec0k(
    const float* __restrict__ w, const float* __restrict__ bias,
    float* __restrict__ seq, const float* __restrict__ zx,
    const float* __restrict__ hin, const float* __restrict__ cin,
    float* __restrict__ hout, float* __restrict__ cout,
    int t0, int tn)
{
    __shared__ float wl[96 * 128];     // h rows only (ci 0..31 -> w row 32+ci)
    __shared__ float hp[32 * RS];
    __shared__ float zs[4 * 32 * 64];
    __shared__ float bs[128];

    const int tid = threadIdx.x, b = blockIdx.x;
    const int kg = tid >> 8, r = tid & 255;
    const int ch = r >> 3, f0 = (r & 7) * 8;

    for (int idx = tid; idx < 96 * 128; idx += 512) {
        int k = idx >> 7, rr = idx & 127;
        int c8 = rr >> 2, g = rr & 3;
        int ci = k / 3, d = k - ci * 3;
        wl[idx] = w[((g * 32 + c8) * 64 + 32 + ci) * 9 + d * 3 + 1];
    }
    if (tid < 128) bs[tid] = bias[tid];
    for (int i = tid; i < 32 * RS; i += 512) hp[i] = 0.f;
    __syncthreads();
    for (int i = tid; i < 2048; i += 512) {
        int c8 = i >> 6, f = i & 63;
        hp[c8 * RS + 4 + f] = hin[b * 2048 + i];
    }
    const float bi = bs[ch], bf = bs[32 + ch], bo = bs[64 + ch], bg = bs[96 + ch];
    const float4 z4 = make_float4(0.f, 0.f, 0.f, 0.f);
    float4 ca = z4, cb4 = z4;
    if (kg == 0) {
        ca  = ldf4(&cin[b * 2048 + ch * 64 + f0]);
        cb4 = ldf4(&cin[b * 2048 + ch * 64 + f0 + 4]);
    }
    __syncthreads();

#pragma unroll 1
    for (int tl = 0; tl < tn; ++tl) {
        const int t = t0 + tl;
        // prefetch x-part gate pre-activations (kg0; used in P2)
        float4 xi0=z4,xi1=z4,xf0=z4,xf1=z4,xo0=z4,xo1=z4,xg0=z4,xg1=z4;
        if (kg == 0) {
            const float* zp0 = &zx[((size_t)tl * B_ + b) * 8192 + ch * 64 + f0];
            xi0 = ldf4(zp0);        xi1 = ldf4(zp0 + 4);
            xf0 = ldf4(zp0 + 2048); xf1 = ldf4(zp0 + 2052);
            xo0 = ldf4(zp0 + 4096); xo1 = ldf4(zp0 + 4100);
            xg0 = ldf4(zp0 + 6144); xg1 = ldf4(zp0 + 6148);
        }
        float4 I0=z4,I1=z4,F0=z4,F1=z4,O0=z4,O1=z4,G0=z4,G1=z4;
#pragma unroll 1
        for (int j = 0; j < 16; ++j) {
            const int ci = kg * 16 + j;
            rowacc8<128>(&hp[ci * RS + 4 + f0], &wl[(ci * 3) * 128 + ch * 4],
                         I0, I1, F0, F1, O0, O1, G0, G1);
        }
        if (kg == 1) {
            stf4(&zs[(0*32+ch)*64 + f0], I0); stf4(&zs[(0*32+ch)*64 + f0 + 4], I1);
            stf4(&zs[(1*32+ch)*64 + f0], F0); stf4(&zs[(1*32+ch)*64 + f0 + 4], F1);
            stf4(&zs[(2*32+ch)*64 + f0], O0); stf4(&zs[(2*32+ch)*64 + f0 + 4], O1);
            stf4(&zs[(3*32+ch)*64 + f0], G0); stf4(&zs[(3*32+ch)*64 + f0 + 4], G1);
        }
        __syncthreads();
        if (kg == 0) {
            float4 zi0 = add4(add4(I0, xi0), ldf4(&zs[(0*32+ch)*64 + f0]));
            float4 zi1 = add4(add4(I1, xi1), ldf4(&zs[(0*32+ch)*64 + f0 + 4]));
            float4 zf0 = add4(add4(F0, xf0), ldf4(&zs[(1*32+ch)*64 + f0]));
            float4 zf1 = add4(add4(F1, xf1), ldf4(&zs[(1*32+ch)*64 + f0 + 4]));
            float4 zo0 = add4(add4(O0, xo0), ldf4(&zs[(2*32+ch)*64 + f0]));
            float4 zo1 = add4(add4(O1, xo1), ldf4(&zs[(2*32+ch)*64 + f0 + 4]));
            float4 zg0 = add4(add4(G0, xg0), ldf4(&zs[(3*32+ch)*64 + f0]));
            float4 zg1 = add4(add4(G1, xg1), ldf4(&zs[(3*32+ch)*64 + f0 + 4]));
            float4 h0q = gate4(zi0, zf0, zo0, zg0, bi, bf, bo, bg, ca);
            float4 h1q = gate4(zi1, zf1, zo1, zg1, bi, bf, bo, bg, cb4);
            stf4(&hp[ch * RS + 4 + f0], h0q);
            stf4(&hp[ch * RS + 4 + f0 + 4], h1q);
            float* sp = &seq[((size_t)t * B_ + b) * 2048 + ch * 64 + f0];
            stf4(sp, h0q); stf4(sp + 4, h1q);
        }
        __syncthreads();
    }

    for (int i = tid; i < 2048; i += 512) {
        int c8 = i >> 6, f = i & 63;
        hout[b * 2048 + i] = hp[c8 * RS + 4 + f];
    }
    if (kg == 0) {
        stf4(&cout[b * 2048 + ch * 64 + f0], ca);
        stf4(&cout[b * 2048 + ch * 64 + f0 + 4], cb4);
    }
}

// ---------------------------------------------------------------------------
// dec1k: decoder L1 h-recurrence + final 1x1 conv. 512 thr, kg=2, FT=4.
// fc for step t-1 is computed in P1(t) (hp holds h(t-1) there); tail after loop.
// ---------------------------------------------------------------------------
__global__ __launch_bounds__(512, 1) void dec1k(
    const float* __restrict__ w, const float* __restrict__ bias,
    const float* __restrict__ zx,
    const float* __restrict__ hin, const float* __restrict__ cin,
    float* __restrict__ hout, float* __restrict__ cout,
    const float* __restrict__ fw, const float* __restrict__ fb,
    float* __restrict__ out, int t0, int tn)
{
    __shared__ float wl[48 * 64];      // h rows only (ci 0..15 -> w row 32+ci)
    __shared__ float hp[16 * RS];
    __shared__ float zs[4 * 16 * 64];
    __shared__ float bs[64];
    __shared__ float fcw[16];
    __shared__ float fcb;

    const int tid = threadIdx.x, b = blockIdx.x;
    const int kg = tid >> 8, r = tid & 255;
    const int ch = r >> 4, f0 = (r & 15) * 4;

    for (int idx = tid; idx < 48 * 64; idx += 512) {
        int k = idx >> 6, rr = idx & 63;
        int c8 = rr >> 2, g = rr & 3;
        int ci = k / 3, d = k - ci * 3;
        wl[idx] = w[((g * 16 + c8) * 48 + 32 + ci) * 9 + d * 3 + 1];
    }
    if (tid < 64) bs[tid] = bias[tid];
    if (tid < 16) fcw[tid] = fw[tid];
    if (tid == 16) fcb = fb[0];
    for (int i = tid; i < 16 * RS; i += 512) hp[i] = 0.f;
    __syncthreads();
    for (int i = tid; i < 1024; i += 512) {
        int c8 = i >> 6, f = i & 63;
        hp[c8 * RS + 4 + f] = hin[b * 1024 + i];
    }
    const float bi = bs[ch], bf = bs[16 + ch], bo = bs[32 + ch], bg = bs[48 + ch];
    const float4 z4 = make_float4(0.f, 0.f, 0.f, 0.f);
    float4 cc = z4;
    if (kg == 0) cc = ldf4(&cin[b * 1024 + ch * 64 + f0]);
    const float fcbv = fcb;
    __syncthreads();

#pragma unroll 1
    for (int tl = 0; tl < tn; ++tl) {
        const int t = t0 + tl;
        // fc for previous step (hp holds h(t-1); read-only phase)
        if (tid < 64 && t > 0) {
            float a = fcbv;
#pragma unroll
            for (int k2 = 0; k2 < 16; ++k2)
                a = fmaf(fcw[k2], hp[k2 * RS + 4 + tid], a);
            out[(b * T_ + (t - 1)) * 64 + tid] = a;
        }
        float4 xi=z4, xf=z4, xo=z4, xg=z4;
        if (kg == 0) {
            const float* zp0 = &zx[((size_t)tl * B_ + b) * 4096 + ch * 64 + f0];
            xi = ldf4(zp0);
            xf = ldf4(zp0 + 1024);
            xo = ldf4(zp0 + 2048);
            xg = ldf4(zp0 + 3072);
        }
        float4 ai = z4, af = z4, ao = z4, ag = z4;
#pragma unroll 1
        for (int j = 0; j < 8; ++j) {
            const int ci = kg * 8 + j;
            rowacc4<64>(&hp[ci * RS + 4 + f0], &wl[(ci * 3) * 64 + ch * 4],
                        ai, af, ao, ag);
        }
        if (kg == 1) {
            stf4(&zs[(0*16+ch)*64 + f0], ai);
            stf4(&zs[(1*16+ch)*64 + f0], af);
            stf4(&zs[(2*16+ch)*64 + f0], ao);
            stf4(&zs[(3*16+ch)*64 + f0], ag);
        }
        __syncthreads();
        if (kg == 0) {
            float4 zi = add4(add4(ai, xi), ldf4(&zs[(0*16+ch)*64 + f0]));
            float4 zf = add4(add4(af, xf), ldf4(&zs[(1*16+ch)*64 + f0]));
            float4 zo = add4(add4(ao, xo), ldf4(&zs[(2*16+ch)*64 + f0]));
            float4 zg = add4(add4(ag, xg), ldf4(&zs[(3*16+ch)*64 + f0]));
            float4 hq = gate4(zi, zf, zo, zg, bi, bf, bo, bg, cc);
            stf4(&hp[ch * RS + 4 + f0], hq);
        }
        __syncthreads();
    }

    // tail: fc for last step of this chunk
    if (tid < 64) {
        float a = fcbv;
#pragma unroll
        for (int k2 = 0; k2 < 16; ++k2)
            a = fmaf(fcw[k2], hp[k2 * RS + 4 + tid], a);
        out[(b * T_ + (t0 + tn - 1)) * 64 + tid] = a;
    }
    for (int i = tid; i < 1024; i += 512) {
        int c8 = i >> 6, f = i & 63;
        hout[b * 1024 + i] = hp[c8 * RS + 4 + f];
    }
    if (kg == 0) stf4(&cout[b * 1024 + ch * 64 + f0], cc);
}

// ---------------------------------------------------------------------------
// Fallback (ws too small for zx): fused x+h decoders (round-4 structure).
// ---------------------------------------------------------------------------
__global__ __launch_bounds__(512, 1) void dec0_fb(
    const float* __restrict__ w, const float* __restrict__ bias,
    float* __restrict__ seq,
    const float* __restrict__ hin, const float* __restrict__ cin)
{
    __shared__ float wl[192 * 128];
    __shared__ float bs[128];
    __shared__ float xin[32 * RS];
    __shared__ float hp[32 * RS];

    const int tid = threadIdx.x;
    const int b = blockIdx.x;

    for (int idx = tid; idx < 192 * 128; idx += 512) {
        int k = idx >> 7, rr = idx & 127;
        int ch = rr >> 2, g = rr & 3;
        int ci = k / 3, d = k - ci * 3;
        wl[idx] = w[((g * 32 + ch) * 64 + ci) * 9 + d * 3 + 1];
    }
    if (tid < 128) bs[tid] = bias[tid];
    for (int i = tid; i < 32 * RS; i += 512) { xin[i] = 0.f; hp[i] = 0.f; }
    __syncthreads();
    {
        const float* hs = &hin[b * 2048 + tid * 4];
        float4 hv = ldf4(hs);
        int ci = tid >> 4, col = (tid & 15) * 4;
        stf4(&hp[ci * RS + 4 + col], hv);
    }
    const int ch = tid >> 4, f0 = (tid & 15) * 4;
    float4 cc = ldf4(&cin[b * 2048 + ch * 64 + f0]);
    const float bi = bs[ch], bf = bs[32 + ch], bo = bs[64 + ch], bg = bs[96 + ch];
    const float4 z4 = make_float4(0.f,0.f,0.f,0.f);

    float4 nx = ldf4(&seq[(size_t)b * 2048 + tid * 4]);

#pragma unroll 1
    for (int t = 0; t < T_; ++t) {
        {
            int ci = tid >> 4, col = (tid & 15) * 4;
            stf4(&xin[ci * RS + 4 + col], nx);
        }
        __syncthreads();
        if (t + 1 < T_)
            nx = ldf4(&seq[((size_t)(t + 1) * B_ + b) * 2048 + tid * 4]);
        float4 ai = z4, af = z4, ao = z4, ag = z4;
#pragma unroll 1
        for (int rr = 0; rr < 32; ++rr)
            rowacc4<128>(&xin[rr * RS + 4 + f0], wl + (rr * 3) * 128 + ch * 4, ai, af, ao, ag);
#pragma unroll 1
        for (int rr = 0; rr < 32; ++rr)
            rowacc4<128>(&hp[rr * RS + 4 + f0], wl + ((32 + rr) * 3) * 128 + ch * 4, ai, af, ao, ag);
        float4 hn = gate4(ai, af, ao, ag, bi, bf, bo, bg, cc);
        __syncthreads();
        stf4(&hp[ch * RS + 4 + f0], hn);
        stf4(&seq[((size_t)t * B_ + b) * 2048 + ch * 64 + f0], hn);
    }
}

__global__ __launch_bounds__(512, 1) void dec1_fb(
    const float* __restrict__ w, const float* __restrict__ bias,
    const float* __restrict__ seq,
    const float* __restrict__ hin, const float* __restrict__ cin,
    const float* __restrict__ fw, const float* __restrict__ fb,
    float* __restrict__ out)
{
    __shared__ float wl[144 * 64];
    __shared__ float bs[64];
    __shared__ float xin[32 * RS];
    __shared__ float hp[16 * RS];
    __shared__ float fcw[16];
    __shared__ float fcb;

    const int tid = threadIdx.x;
    const int b = blockIdx.x;

    for (int idx = tid; idx < 144 * 64; idx += 512) {
        int k = idx >> 6, rr = idx & 63;
        int ch = rr >> 2, g = rr & 3;
        int ci = k / 3, d = k - ci * 3;
        wl[idx] = w[((g * 16 + ch) * 48 + ci) * 9 + d * 3 + 1];
    }
    if (tid < 64) bs[tid] = bias[tid];
    if (tid < 16) fcw[tid] = fw[tid];
    if (tid == 16) fcb = fb[0];
    for (int i = tid; i < 32 * RS; i += 512) xin[i] = 0.f;
    for (int i = tid; i < 16 * RS; i += 512) hp[i] = 0.f;
    __syncthreads();
    {
        const float* hs = &hin[b * 1024 + tid * 2];
        float2 hv = *reinterpret_cast<const float2*>(hs);
        int ci = tid >> 5, col = (tid & 31) * 2;
        *reinterpret_cast<float2*>(&hp[ci * RS + 4 + col]) = hv;
    }
    const int ch = tid >> 5, f0 = (tid & 31) * 2;
    float2 cc = *reinterpret_cast<const float2*>(&cin[b * 1024 + ch * 64 + f0]);
    const float bi = bs[ch], bf = bs[16 + ch], bo = bs[32 + ch], bg = bs[48 + ch];
    const float2 z2 = make_float2(0.f,0.f);
    float4 nx = ldf4(&seq[(size_t)b * 2048 + tid * 4]);
    __syncthreads();

#pragma unroll 1
    for (int t = 0; t < T_; ++t) {
        {
            int ci = tid >> 4, col = (tid & 15) * 4;
            stf4(&xin[ci * RS + 4 + col], nx);
        }
        __syncthreads();
        if (t + 1 < T_)
            nx = ldf4(&seq[((size_t)(t + 1) * B_ + b) * 2048 + tid * 4]);

        float2 ai = z2, af = z2, ao = z2, ag = z2;
#pragma unroll 1
        for (int rr = 0; rr < 32; ++rr)
            rowacc2<64>(&xin[rr * RS + 4 + f0], wl + (rr * 3) * 64 + ch * 4, ai, af, ao, ag);
#pragma unroll 1
        for (int rr = 0; rr < 16; ++rr)
            rowacc2<64>(&hp[rr * RS + 4 + f0], wl + ((32 + rr) * 3) * 64 + ch * 4, ai, af, ao, ag);

        float2 hh;
        hh.x = gate1(ai.x + bi, af.x + bf, ao.x + bo, ag.x + bg, cc.x);
        hh.y = gate1(ai.y + bi, af.y + bf, ao.y + bo, ag.y + bg, cc.y);
        __syncthreads();
        *reinterpret_cast<float2*>(&hp[ch * RS + 4 + f0]) = hh;
        __syncthreads();

        if (tid < 64) {
            float a = fcb;
#pragma unroll
            for (int k2 = 0; k2 < 16; ++k2)
                a = fmaf(fcw[k2], hp[k2 * RS + 4 + tid], a);
            out[(b * T_ + t) * 64 + tid] = a;
        }
    }
}

// ---------------------------------------------------------------------------
extern "C" void kernel_launch(void* const* d_in, const int* in_sizes, int n_in,
                              void* d_out, int out_size, void* d_ws, size_t ws_size,
                              hipStream_t stream)
{
    (void)in_sizes; (void)n_in; (void)out_size;
    const float* x   = (const float*)d_in[0];
    const float* ew0 = (const float*)d_in[1];
    const float* eb0 = (const float*)d_in[2];
    const float* ew1 = (const float*)d_in[3];
    const float* eb1 = (const float*)d_in[4];
    const float* dw0 = (const float*)d_in[5];
    const float* db0 = (const float*)d_in[6];
    const float* dw1 = (const float*)d_in[7];
    const float* db1 = (const float*)d_in[8];
    const float* fw  = (const float*)d_in[9];
    const float* fb  = (const float*)d_in[10];
    float* out = (float*)d_out;

    float* ws  = (float*)d_ws;
    size_t off = 0;
    float* seq = ws + off; off += (size_t)T_ * B_ * 2048;
    float* h1f = ws + off; off += (size_t)B_ * 1024;
    float* c1f = ws + off; off += (size_t)B_ * 1024;
    float* h2f = ws + off; off += (size_t)B_ * 2048;
    float* c2f = ws + off; off += (size_t)B_ * 2048;
    float* hd0 = ws + off; off += (size_t)B_ * 2048;
    float* cd0 = ws + off; off += (size_t)B_ * 2048;
    float* hd1 = ws + off; off += (size_t)B_ * 1024;
    float* cd1 = ws + off; off += (size_t)B_ * 1024;
    float* zx  = ws + off;

    size_t availf = (ws_size / 4 > off) ? (ws_size / 4 - off) : 0;
    int TC = 0;
    if      (availf >= (size_t)100 * B_ * 8192) TC = 100;
    else if (availf >= (size_t)50  * B_ * 8192) TC = 50;
    else if (availf >= (size_t)25  * B_ * 8192) TC = 25;
    else if (availf >= (size_t)10  * B_ * 8192) TC = 10;

    enc_kernel<<<B_, 512, 0, stream>>>(x, ew0, eb0, ew1, eb1, seq, h1f, c1f, h2f, c2f);

    if (TC > 0) {
        for (int t0 = 0; t0 < T_; t0 += TC) {
            xconv0_kernel<<<TC * B_, 256, 0, stream>>>(seq, dw0, zx, t0);
            dec0k<<<B_, 512, 0, stream>>>(
                dw0, db0, seq, zx,
                t0 == 0 ? h2f : hd0, t0 == 0 ? c2f : cd0, hd0, cd0, t0, TC);
        }
        for (int t0 = 0; t0 < T_; t0 += TC) {
            xconv1_kernel<<<TC * B_, 256, 0, stream>>>(seq, dw1, zx, t0);
            dec1k<<<B_, 512, 0, stream>>>(
                dw1, db1, zx,
                t0 == 0 ? h1f : hd1, t0 == 0 ? c1f : cd1, hd1, cd1,
                fw, fb, out, t0, TC);
        }
    } else {
        dec0_fb<<<B_, 512, 0, stream>>>(dw0, db0, seq, h2f, c2f);
        dec1_fb<<<B_, 512, 0, stream>>>(dw1, db1, seq, h1f, c1f, fw, fb, out);
    }
}